// Round 19
// baseline (179.162 us; speedup 1.0000x reference)
//
#include <hip/hip_runtime.h>
#include <hip/hip_bf16.h>
#include <stdint.h>

// Problem dims
#define NB 8
#define NSQ 1024
#define NSK 1024
#define ND 1024
#define NH 16
#define NDH 64
#define NM (NB * NSQ)   // 8192 rows
#define LOG2E 1.4426950408889634f

typedef __bf16 bf16;
typedef __bf16 bf16x8 __attribute__((ext_vector_type(8)));
typedef float f32x4 __attribute__((ext_vector_type(4)));
typedef float f32x16 __attribute__((ext_vector_type(16)));
typedef unsigned int uint32;

// ---------------- async global->LDS (16B per lane) ----------------
__device__ __forceinline__ void async_load16(const void* g, void* l) {
  __builtin_amdgcn_global_load_lds(
      (__attribute__((address_space(1))) void*)g,
      (__attribute__((address_space(3))) void*)l, 16, 0, 0);
}

// half-swap: x' = {x.lo, y.lo}, y' = {x.hi, y.hi}
__device__ __forceinline__ void permswap(uint32& x, uint32& y) {
#if __has_builtin(__builtin_amdgcn_permlane32_swap)
  auto r = __builtin_amdgcn_permlane32_swap(x, y, false, false);
  x = r[0]; y = r[1];
#else
  asm volatile("v_permlane32_swap_b32 %0, %1" : "+v"(x), "+v"(y));
#endif
}

// ---------------- f32 -> bf16 converter (Q and K fused, grid.y selects) ----------------
__global__ __launch_bounds__(256) void cvt2_f32_bf16(const float* __restrict__ A,
                                                     const float* __restrict__ B,
                                                     bf16* __restrict__ Oa,
                                                     bf16* __restrict__ Ob) {
  const float* in = blockIdx.y ? B : A;
  bf16* out = blockIdx.y ? Ob : Oa;
  int i = blockIdx.x * 256 + threadIdx.x;
  float4 v = *(const float4*)(in + (size_t)i * 4);
  union { uint64_t u; bf16 h[4]; } o;
  o.h[0] = (bf16)v.x; o.h[1] = (bf16)v.y; o.h[2] = (bf16)v.z; o.h[3] = (bf16)v.w;
  *(uint64_t*)(out + (size_t)i * 4) = o.u;
}

// ---------------- 4x W [K,N] f32 -> Wt [N,K] bf16 (fused, grid.z selects) ----------------
__global__ __launch_bounds__(256) void transpose_cvt4(
    const float* __restrict__ W0, const float* __restrict__ W1,
    const float* __restrict__ W2, const float* __restrict__ W3,
    bf16* __restrict__ O0, bf16* __restrict__ O1,
    bf16* __restrict__ O2, bf16* __restrict__ O3) {
  const float* W; bf16* Wt;
  switch (blockIdx.z) {
    case 0: W = W0; Wt = O0; break;
    case 1: W = W1; Wt = O1; break;
    case 2: W = W2; Wt = O2; break;
    default: W = W3; Wt = O3; break;
  }
  __shared__ float t[64][65];
  const int bc = blockIdx.x * 64;
  const int br = blockIdx.y * 64;
  const int tid = threadIdx.x;
  for (int c = tid; c < 1024; c += 256) {
    int r = c >> 4, off = (c & 15) * 4;
    float4 v = *(const float4*)&W[(size_t)(br + r) * 1024 + bc + off];
    t[r][off] = v.x; t[r][off + 1] = v.y; t[r][off + 2] = v.z; t[r][off + 3] = v.w;
  }
  __syncthreads();
  for (int c = tid; c < 512; c += 256) {
    int cc = c >> 3, rr = (c & 7) * 8;
    union { uint4 u; bf16 h[8]; } o;
#pragma unroll
    for (int i = 0; i < 8; ++i) o.h[i] = (bf16)t[rr + i][cc];
    *(uint4*)&Wt[(size_t)(bc + cc) * 1024 + br + rr] = o.u;
  }
}

// ---------------- v (from kvb, stride 2048, offset 1024) -> vT [B,H,DH,SK] ----------------
__global__ __launch_bounds__(256) void transpose_v(const bf16* __restrict__ vsrc,
                                                   bf16* __restrict__ vT) {
  const int st = blockIdx.x * 64;
  const int bh = blockIdx.y;
  const int b = bh >> 4, h = bh & 15;
  __shared__ __align__(16) bf16 t[64][72];
  const int tid = threadIdx.x;
  for (int c = tid; c < 512; c += 256) {
    int s = c >> 3, off = (c & 7) * 8;
    *(uint4*)&t[s][off] =
        *(const uint4*)&vsrc[(size_t)(b * NSK + st + s) * 2048 + 1024 + h * NDH + off];
  }
  __syncthreads();
  for (int c = tid; c < 512; c += 256) {
    int d = c >> 3, s0 = (c & 7) * 8;
    union { uint4 u; bf16 h[8]; } o;
#pragma unroll
    for (int i = 0; i < 8; ++i) o.h[i] = t[s0 + i][d];
    *(uint4*)&vT[((size_t)(bh * NDH + d)) * NSK + st + s0] = o.u;
  }
}

// ---------------- gemm16w: KV GEMM at 16 waves/CU (bf16 A, R16-proven) ----------------
// 128x256 block, 8 waves (2M x 4N, each 64x64 out), BK=32, TRIPLE-buffered LDS
// (72 KB -> 2 blocks/CU = 16 waves/CU = 4 waves/SIMD). Stage AFTER ds_reads,
// counted vmcnt(3), trailing lgkm0+barrier, granule-XOR swizzle, XCD swizzle.
// Grid = 512 (64 Mtiles x 8 Ntiles). Epilogue: col<1024 -> (acc+bk)*LOG2E else acc+bv.
__global__ __launch_bounds__(512, 4) void gemm16w(
    const bf16* __restrict__ Ab, const bf16* __restrict__ Bt,
    const float* __restrict__ bk_, const float* __restrict__ bv_,
    bf16* __restrict__ Cb) {
  constexpr int NT = 32;                 // K = 1024 = 32 x 32
  __shared__ __align__(16) bf16 Asl[3][128 * 32];
  __shared__ __align__(16) bf16 Bsl[3][256 * 32];

  const int tid = threadIdx.x;
  const int flat = blockIdx.x;
  const int xi = (flat & 7) * 64 + (flat >> 3);   // 512 blocks -> bijective
  const int bcol = (xi & 7) * 256;
  const int brow = (xi >> 3) * 128;

  const int w = tid >> 6, lane = tid & 63;
  const int wm = w >> 2, wn = w & 3;              // 2M x 4N waves
  const int lr = lane & 15, l4 = lane >> 4;
  const int rgrp = l4 * 4;
  const int gph = (l4 ^ ((lr >> 1) & 3)) * 8;     // read-side swizzled granule

  const int srow = tid >> 2;                      // 0..127
  const int gsrc = (tid & 3) ^ ((tid >> 3) & 3);
  const bf16* Ag = Ab + (size_t)(brow + srow) * 1024 + gsrc * 8;
  const bf16* Bg = Bt + (size_t)(bcol + srow) * 1024 + gsrc * 8;
  const int ldo = srow * 32 + (tid & 3) * 8;

  auto stage = [&](int d, int kt) {   // 1 A round + 2 B rounds = 3 loads/thread
    async_load16(Ag + kt * 32, &Asl[d][ldo]);
#pragma unroll
    for (int r = 0; r < 2; ++r)
      async_load16(Bg + (size_t)r * (128 * 1024) + kt * 32, &Bsl[d][r * 4096 + ldo]);
  };

  f32x4 acc[4][4] = {};

  stage(0, 0);
  stage(1, 1);
  asm volatile("s_waitcnt vmcnt(3)" ::: "memory");   // tile 0 landed
  __builtin_amdgcn_s_barrier();

  int cur = 0, st2 = 2;
  for (int t = 0; t < NT; ++t) {
    bf16x8 af[4], bfr[4];
#pragma unroll
    for (int i = 0; i < 4; ++i)
      af[i] = *(const bf16x8*)&Asl[cur][(wm * 64 + i * 16 + lr) * 32 + gph];
#pragma unroll
    for (int n = 0; n < 4; ++n)
      bfr[n] = *(const bf16x8*)&Bsl[cur][(wn * 64 + n * 16 + lr) * 32 + gph];
    if (t + 2 < NT) stage(st2, t + 2);   // buffer last read at t-1 (pinned)
    __builtin_amdgcn_s_setprio(1);
#pragma unroll
    for (int i = 0; i < 4; ++i)
#pragma unroll
      for (int n = 0; n < 4; ++n)
        acc[i][n] = __builtin_amdgcn_mfma_f32_16x16x32_bf16(af[i], bfr[n], acc[i][n], 0, 0, 0);
    __builtin_amdgcn_s_setprio(0);
    if (t + 2 < NT)      asm volatile("s_waitcnt vmcnt(3)" ::: "memory");
    else if (t + 1 < NT) asm volatile("s_waitcnt vmcnt(0)" ::: "memory");
    asm volatile("s_waitcnt lgkmcnt(0)" ::: "memory");
    __builtin_amdgcn_s_barrier();
    cur = (cur == 2) ? 0 : cur + 1;
    st2 = (st2 == 2) ? 0 : st2 + 1;
  }

  const bool isV = (bcol >= 1024);
#pragma unroll
  for (int m = 0; m < 4; ++m) {
#pragma unroll
    for (int n = 0; n < 4; ++n) {
      const int col = bcol + wn * 64 + n * 16 + lr;
      const float bvv = isV ? bv_[col - 1024] : bk_[col];
      const float sc = isV ? 1.0f : LOG2E;
#pragma unroll
      for (int r = 0; r < 4; ++r) {
        const int row = brow + wm * 64 + m * 16 + rgrp + r;
        Cb[(size_t)row * 2048 + col] = (bf16)((acc[m][n][r] + bvv) * sc);
      }
    }
  }
}

// ---------------- gemm3b: C[M,N] = f(A[M,1024] @ Bt[N,1024]^T) (bf16 A, R10-proven) --
// BM x 128 block, 4 waves (2x2), BK=32, TRIPLE-buffered LDS, one barrier + counted
// vmcnt per K-tile, 2-tile-deep prefetch (stage AFTER ds_reads), granule-XOR swizzle.
// MODE 0: Cb = bf16((acc+bias)*scale).  MODE 1: Cb = bf16(Res + relu(acc+bias)).
template <int BM, int MODE, int NXC>
__global__ __launch_bounds__(256, 2) void gemm3b(
    const bf16* __restrict__ Ab, const bf16* __restrict__ Bt,
    const float* __restrict__ bias,
    bf16* __restrict__ Cb, const bf16* __restrict__ Resb, float scale, int N) {
  constexpr int NT = 32;
  constexpr int AR = BM / 64;
  constexpr int MR = BM / 32;
  __shared__ __align__(16) bf16 Asl[3][BM * 32];
  __shared__ __align__(16) bf16 Bsl[3][128 * 32];

  const int tid = threadIdx.x;
  const int flat = blockIdx.x;
  const int xi = (flat & 7) * 64 + (flat >> 3);
  const int bcol = (xi & (NXC - 1)) * 128;
  const int brow = (xi / NXC) * BM;

  const int w = tid >> 6, lane = tid & 63;
  const int wm = w >> 1, wn = w & 1;
  const int lr = lane & 15, l4 = lane >> 4;
  const int rgrp = l4 * 4;
  const int gph = (l4 ^ ((lr >> 1) & 3)) * 8;

  const int srow = tid >> 2;
  const int gsrc = (tid & 3) ^ ((tid >> 3) & 3);
  const bf16* Bg = Bt + (size_t)(bcol + srow) * 1024 + gsrc * 8;
  const int ldo = srow * 32 + (tid & 3) * 8;

  auto stage = [&](int d, int kt) {
#pragma unroll
    for (int r = 0; r < AR; ++r)
      async_load16(Ab + (size_t)(brow + srow + r * 64) * 1024 + gsrc * 8 + kt * 32,
                   &Asl[d][r * 2048 + ldo]);
#pragma unroll
    for (int r = 0; r < 2; ++r)
      async_load16(Bg + (size_t)r * (64 * 1024) + kt * 32, &Bsl[d][r * 2048 + ldo]);
  };
  auto wait_tile = [&]() {
    if constexpr (BM == 256) asm volatile("s_waitcnt vmcnt(6)" ::: "memory");
    else                     asm volatile("s_waitcnt vmcnt(4)" ::: "memory");
  };

  f32x4 acc[MR][4] = {};

  stage(0, 0);
  stage(1, 1);
  wait_tile();
  __builtin_amdgcn_s_barrier();

  int cur = 0, st2 = 2;
  for (int t = 0; t < NT; ++t) {
    bf16x8 af[MR], bfr[4];
#pragma unroll
    for (int i = 0; i < MR; ++i)
      af[i] = *(const bf16x8*)&Asl[cur][(wm * (BM / 2) + i * 16 + lr) * 32 + gph];
#pragma unroll
    for (int n = 0; n < 4; ++n)
      bfr[n] = *(const bf16x8*)&Bsl[cur][(wn * 64 + n * 16 + lr) * 32 + gph];
    if (t + 2 < NT) stage(st2, t + 2);
    __builtin_amdgcn_s_setprio(1);
#pragma unroll
    for (int i = 0; i < MR; ++i)
#pragma unroll
      for (int n = 0; n < 4; ++n)
        acc[i][n] = __builtin_amdgcn_mfma_f32_16x16x32_bf16(af[i], bfr[n], acc[i][n], 0, 0, 0);
    __builtin_amdgcn_s_setprio(0);
    if (t + 2 < NT)      wait_tile();
    else if (t + 1 < NT) asm volatile("s_waitcnt vmcnt(0)" ::: "memory");
    asm volatile("s_waitcnt lgkmcnt(0)" ::: "memory");
    __builtin_amdgcn_s_barrier();
    cur = (cur == 2) ? 0 : cur + 1;
    st2 = (st2 == 2) ? 0 : st2 + 1;
  }

#pragma unroll
  for (int m = 0; m < MR; ++m) {
#pragma unroll
    for (int n = 0; n < 4; ++n) {
      const int col = bcol + wn * 64 + n * 16 + lr;
      const float bv = bias[col];
#pragma unroll
      for (int r = 0; r < 4; ++r) {
        const int row = brow + wm * (BM / 2) + m * 16 + rgrp + r;
        float v = acc[m][n][r] + bv;
        if (MODE == 1) {
          float res = (float)Resb[(size_t)row * N + col];
          Cb[(size_t)row * N + col] = (bf16)(res + (v > 0.f ? v : 0.f));
        } else {
          Cb[(size_t)row * N + col] = (bf16)(v * scale);
        }
      }
    }
  }
}

// ---------------- fused attention: 8 waves x 32 q, 32x32 MFMA, in-register P ----------
// 1-D grid of 512 blocks, XCD-remapped so all 4 q-blocks of one (b,h) share an XCD
// (K/V panels become L2-resident; verified FETCH 73.8 -> 24.6 MB).
__global__ __launch_bounds__(512, 4) void attn_kernel(
    const bf16* __restrict__ qb, const bf16* __restrict__ kvb,
    const bf16* __restrict__ vT, bf16* __restrict__ attnout) {
  const int bid = blockIdx.x;
  const int bh = (bid & 7) * 16 + ((bid >> 3) & 15);
  const int qi = bid >> 7;
  const int b = bh >> 4, h = bh & 15;
  const int tid = threadIdx.x, w = tid >> 6, lane = tid & 63;
  const int l31 = lane & 31;
  const int l1 = lane >> 5;
  const int q0w = qi * 256 + w * 32;

  __shared__ __align__(16) bf16 Kl[2][64 * 64];
  __shared__ __align__(16) bf16 Vl[2][64 * 64];

  const int srow = tid >> 3;
  const int sgran = tid & 7;
  const int gsw = sgran ^ (srow & 7);
  const int ldst = srow * 64 + sgran * 8;
  const int rg = l31 & 7;

  const bf16* kbase = kvb + (size_t)(b * NSK) * 2048 + h * NDH;
  const bf16* vbase = vT + (size_t)(bh * NDH) * NSK;

  bf16x8 qf[4];
#pragma unroll
  for (int kd = 0; kd < 4; ++kd)
    qf[kd] = *(const bf16x8*)&qb[(size_t)(b * NSQ + q0w + l31) * ND +
                                 h * NDH + kd * 16 + l1 * 8];

  f32x16 oacc0 = {}, oacc1 = {}, lacc = {};
  bf16x8 ones;
#pragma unroll
  for (int i = 0; i < 8; ++i) ones[i] = (bf16)1.0f;

  auto stage = [&](int bi, int kt) {
    async_load16(kbase + (size_t)(kt + srow) * 2048 + gsw * 8, &Kl[bi][ldst]);
    async_load16(vbase + (size_t)srow * NSK + kt + gsw * 8, &Vl[bi][ldst]);
  };

  stage(0, 0);

  for (int t = 0; t < 16; ++t) {
    const int bi = t & 1;
    asm volatile("s_waitcnt vmcnt(0)" ::: "memory");
    __syncthreads();
    if (t < 15) stage(bi ^ 1, (t + 1) * 64);

    uint32 W[2][4][2];
#pragma unroll
    for (int n = 0; n < 2; ++n) {
      f32x16 s = {};
      __builtin_amdgcn_s_setprio(1);
#pragma unroll
      for (int kd = 0; kd < 4; ++kd) {
        bf16x8 kf = *(const bf16x8*)&Kl[bi][(n * 32 + l31) * 64 + (((kd * 2 + l1) ^ rg) * 8)];
        s = __builtin_amdgcn_mfma_f32_32x32x16_bf16(kf, qf[kd], s, 0, 0, 0);
      }
      __builtin_amdgcn_s_setprio(0);
#pragma unroll
      for (int r2 = 0; r2 < 4; ++r2)
#pragma unroll
        for (int p = 0; p < 2; ++p) {
          float elo = __builtin_amdgcn_exp2f(s[r2 * 4 + 2 * p]);
          float ehi = __builtin_amdgcn_exp2f(s[r2 * 4 + 2 * p + 1]);
          uint32 wd;
          asm("v_cvt_pk_bf16_f32 %0, %1, %2" : "=v"(wd) : "v"(elo), "v"(ehi));
          W[n][r2][p] = wd;
        }
    }
    __builtin_amdgcn_s_setprio(1);
#pragma unroll
    for (int kc = 0; kc < 4; ++kc) {
      uint32 x0 = W[kc >> 1][(kc & 1) * 2][0], y0 = W[kc >> 1][(kc & 1) * 2 + 1][0];
      uint32 x1 = W[kc >> 1][(kc & 1) * 2][1], y1 = W[kc >> 1][(kc & 1) * 2 + 1][1];
      permswap(x0, y0);
      permswap(x1, y1);
      union { uint32 u[4]; bf16x8 v; } cvt;
      cvt.u[0] = x0; cvt.u[1] = x1; cvt.u[2] = y0; cvt.u[3] = y1;
      bf16x8 pa = cvt.v;
      bf16x8 vf0 = *(const bf16x8*)&Vl[bi][(l31) * 64 + (((kc * 2 + l1) ^ rg) * 8)];
      bf16x8 vf1 = *(const bf16x8*)&Vl[bi][(32 + l31) * 64 + (((kc * 2 + l1) ^ rg) * 8)];
      oacc0 = __builtin_amdgcn_mfma_f32_32x32x16_bf16(pa, vf0, oacc0, 0, 0, 0);
      oacc1 = __builtin_amdgcn_mfma_f32_32x32x16_bf16(pa, vf1, oacc1, 0, 0, 0);
      lacc = __builtin_amdgcn_mfma_f32_32x32x16_bf16(pa, ones, lacc, 0, 0, 0);
    }
    __builtin_amdgcn_s_setprio(0);
  }

  float inv[16];
#pragma unroll
  for (int r = 0; r < 16; ++r) inv[r] = 1.0f / lacc[r];
#pragma unroll
  for (int r = 0; r < 16; ++r) {
    const int row = q0w + (r & 3) + 8 * (r >> 2) + 4 * l1;
    attnout[(size_t)(b * NSQ + row) * ND + h * NDH + l31] = (bf16)(oacc0[r] * inv[r]);
    attnout[(size_t)(b * NSQ + row) * ND + h * NDH + 32 + l31] = (bf16)(oacc1[r] * inv[r]);
  }
}

// ---------------- LayerNorm over bf16 input ----------------
template <bool RES, bool OUTF>
__global__ __launch_bounds__(256) void ln_kernel(
    const bf16* __restrict__ x, const bf16* __restrict__ rq, float rscale,
    const float* __restrict__ g, const float* __restrict__ be,
    bf16* __restrict__ yb, float* __restrict__ yf) {
  __shared__ float sm[4];
  const int row = blockIdx.x, tid = threadIdx.x;
  const size_t base = (size_t)row * ND + tid * 4;
  union { uint2 u; bf16 h[4]; } xv;
  xv.u = *(const uint2*)(x + base);
  float v0 = (float)xv.h[0], v1 = (float)xv.h[1], v2 = (float)xv.h[2], v3 = (float)xv.h[3];
  if (RES) {
    union { uint2 u; bf16 h[4]; } q;
    q.u = *(const uint2*)(rq + base);
    v0 += rscale * (float)q.h[0]; v1 += rscale * (float)q.h[1];
    v2 += rscale * (float)q.h[2]; v3 += rscale * (float)q.h[3];
  }
  float s = v0 + v1 + v2 + v3;
#pragma unroll
  for (int off = 32; off > 0; off >>= 1) s += __shfl_down(s, off, 64);
  if ((tid & 63) == 0) sm[tid >> 6] = s;
  __syncthreads();
  const float mean = (sm[0] + sm[1] + sm[2] + sm[3]) * (1.0f / ND);
  __syncthreads();
  const float d0 = v0 - mean, d1 = v1 - mean, d2 = v2 - mean, d3 = v3 - mean;
  float sq = d0 * d0 + d1 * d1 + d2 * d2 + d3 * d3;
#pragma unroll
  for (int off = 32; off > 0; off >>= 1) sq += __shfl_down(sq, off, 64);
  if ((tid & 63) == 0) sm[tid >> 6] = sq;
  __syncthreads();
  const float var = (sm[0] + sm[1] + sm[2] + sm[3]) * (1.0f / ND);
  const float rs = rsqrtf(var + 1e-5f);
  float4 gv = *(const float4*)(g + tid * 4);
  float4 bv = *(const float4*)(be + tid * 4);
  const float y0 = d0 * rs * gv.x + bv.x;
  const float y1 = d1 * rs * gv.y + bv.y;
  const float y2 = d2 * rs * gv.z + bv.z;
  const float y3 = d3 * rs * gv.w + bv.w;
  if (OUTF) {
    *(float4*)(yf + base) = make_float4(y0, y1, y2, y3);
  } else {
    union { uint2 u; bf16 h[4]; } o;
    o.h[0] = (bf16)y0; o.h[1] = (bf16)y1; o.h[2] = (bf16)y2; o.h[3] = (bf16)y3;
    *(uint2*)(yb + base) = o.u;
  }
}

extern "C" void kernel_launch(void* const* d_in, const int* in_sizes, int n_in,
                              void* d_out, int out_size, void* d_ws, size_t ws_size,
                              hipStream_t stream) {
  const float* Q  = (const float*)d_in[0];
  const float* K  = (const float*)d_in[1];
  const float* Wq = (const float*)d_in[2];
  const float* bq = (const float*)d_in[3];
  const float* Wk = (const float*)d_in[4];
  const float* bk = (const float*)d_in[5];
  const float* Wv = (const float*)d_in[6];
  const float* bv = (const float*)d_in[7];
  const float* Wo = (const float*)d_in[8];
  const float* bo = (const float*)d_in[9];
  const float* g0 = (const float*)d_in[10];
  const float* b0 = (const float*)d_in[11];
  const float* g1 = (const float*)d_in[12];
  const float* b1 = (const float*)d_in[13];
  float* out = (float*)d_out;

  char* ws = (char*)d_ws;
  const size_t MB = 1024 * 1024;
  bf16* Qb    = (bf16*)(ws + 0);          // 16MB
  bf16* Kb    = (bf16*)(ws + 16 * MB);    // 16MB
  bf16* Wqt   = (bf16*)(ws + 32 * MB);    // 2MB
  bf16* Wkvt  = (bf16*)(ws + 34 * MB);    // 4MB ([2048][1024])
  bf16* Wot   = (bf16*)(ws + 38 * MB);    // 2MB
  bf16* qb    = (bf16*)(ws + 40 * MB);    // 16MB
  bf16* kvb   = (bf16*)(ws + 56 * MB);    // 32MB ([8192][2048]: k | v)
  bf16* vT    = (bf16*)(ws + 88 * MB);    // 16MB
  bf16* attnb = (bf16*)(ws + 104 * MB);   // 16MB
  bf16* h0b   = (bf16*)(ws + 56 * MB);    // reuse kvb (dead after attn)
  bf16* out1b = (bf16*)(ws + 0);          // reuse Qb (dead after q GEMM)

  // 1. weights: transpose + convert (fused x4); Q,K -> bf16 (fused)
  transpose_cvt4<<<dim3(16, 16, 4), 256, 0, stream>>>(
      Wq, Wk, Wv, Wo, Wqt, Wkvt, Wkvt + 1024 * 1024, Wot);
  cvt2_f32_bf16<<<dim3(8192, 2), 256, 0, stream>>>(Q, K, Qb, Kb);
  // 2. projections (q *= 1/32 exact; k *= log2e; v *= 1)
  gemm16w<<<512, 512, 0, stream>>>(Kb, Wkvt, bk, bv, kvb);
  gemm3b<128, 0, 8><<<512, 256, 0, stream>>>(Qb, Wqt, bq, qb, nullptr, 0.03125f, 1024);
  // 3. v -> vT per head
  transpose_v<<<dim3(16, 128), 256, 0, stream>>>(kvb, vT);
  // 4. attention (normalized bf16 out, XCD-remapped grid)
  attn_kernel<<<512, 512, 0, stream>>>(qb, kvb, vT, attnb);
  // 5. h0 = LN(32*qb + attn)
  ln_kernel<true, false><<<8192, 256, 0, stream>>>(attnb, qb, 32.0f, g0, b0, h0b, nullptr);
  // 6. out1 = h0 + relu(h0 @ Wo + bo)
  gemm3b<128, 1, 8><<<512, 256, 0, stream>>>(h0b, Wot, bo, out1b, h0b, 1.0f, 1024);
  // 7. out = LN(out1)
  ln_kernel<false, true><<<8192, 256, 0, stream>>>(out1b, nullptr, 0.f, g1, b1, nullptr, out);
}

// Round 20
// 175.339 us; speedup vs baseline: 1.0218x; 1.0218x over previous
//
#include <hip/hip_runtime.h>
#include <hip/hip_bf16.h>
#include <stdint.h>

// Problem dims
#define NB 8
#define NSQ 1024
#define NSK 1024
#define ND 1024
#define NH 16
#define NDH 64
#define NM (NB * NSQ)   // 8192 rows
#define LOG2E 1.4426950408889634f

typedef __bf16 bf16;
typedef __bf16 bf16x8 __attribute__((ext_vector_type(8)));
typedef float f32x4 __attribute__((ext_vector_type(4)));
typedef float f32x16 __attribute__((ext_vector_type(16)));
typedef unsigned int uint32;

// ---------------- async global->LDS (16B per lane) ----------------
__device__ __forceinline__ void async_load16(const void* g, void* l) {
  __builtin_amdgcn_global_load_lds(
      (__attribute__((address_space(1))) void*)g,
      (__attribute__((address_space(3))) void*)l, 16, 0, 0);
}

// half-swap: x' = {x.lo, y.lo}, y' = {x.hi, y.hi}
__device__ __forceinline__ void permswap(uint32& x, uint32& y) {
#if __has_builtin(__builtin_amdgcn_permlane32_swap)
  auto r = __builtin_amdgcn_permlane32_swap(x, y, false, false);
  x = r[0]; y = r[1];
#else
  asm volatile("v_permlane32_swap_b32 %0, %1" : "+v"(x), "+v"(y));
#endif
}

// ---------------- prep: 4x weight transpose+cvt (z<4) + Q/K cvt (z=4,5) ----------------
__global__ __launch_bounds__(256) void prep_kernel(
    const float* __restrict__ W0, const float* __restrict__ W1,
    const float* __restrict__ W2, const float* __restrict__ W3,
    bf16* __restrict__ O0, bf16* __restrict__ O1,
    bf16* __restrict__ O2, bf16* __restrict__ O3,
    const float* __restrict__ Qf, const float* __restrict__ Kf,
    bf16* __restrict__ Qb, bf16* __restrict__ Kb) {
  if (blockIdx.z >= 4) {
    const float* in = (blockIdx.z == 4) ? Qf : Kf;
    bf16* out = (blockIdx.z == 4) ? Qb : Kb;
    int base = (blockIdx.y * 16 + blockIdx.x) * 256 + threadIdx.x;  // 0..65535
    for (int i = base; i < 2097152; i += 65536) {
      float4 v = *(const float4*)(in + (size_t)i * 4);
      union { uint64_t u; bf16 h[4]; } o;
      o.h[0] = (bf16)v.x; o.h[1] = (bf16)v.y; o.h[2] = (bf16)v.z; o.h[3] = (bf16)v.w;
      *(uint64_t*)(out + (size_t)i * 4) = o.u;
    }
    return;
  }
  const float* W; bf16* Wt;
  switch (blockIdx.z) {
    case 0: W = W0; Wt = O0; break;
    case 1: W = W1; Wt = O1; break;
    case 2: W = W2; Wt = O2; break;
    default: W = W3; Wt = O3; break;
  }
  __shared__ float t[64][65];
  const int bc = blockIdx.x * 64;
  const int br = blockIdx.y * 64;
  const int tid = threadIdx.x;
  for (int c = tid; c < 1024; c += 256) {
    int r = c >> 4, off = (c & 15) * 4;
    float4 v = *(const float4*)&W[(size_t)(br + r) * 1024 + bc + off];
    t[r][off] = v.x; t[r][off + 1] = v.y; t[r][off + 2] = v.z; t[r][off + 3] = v.w;
  }
  __syncthreads();
  for (int c = tid; c < 512; c += 256) {
    int cc = c >> 3, rr = (c & 7) * 8;
    union { uint4 u; bf16 h[8]; } o;
#pragma unroll
    for (int i = 0; i < 8; ++i) o.h[i] = (bf16)t[rr + i][cc];
    *(uint4*)&Wt[(size_t)(bc + cc) * 1024 + br + rr] = o.u;
  }
}

// ---------------- v (from kvb, stride 2048, offset 1024) -> vT [B,H,DH,SK] ----------------
__global__ __launch_bounds__(256) void transpose_v(const bf16* __restrict__ vsrc,
                                                   bf16* __restrict__ vT) {
  const int st = blockIdx.x * 64;
  const int bh = blockIdx.y;
  const int b = bh >> 4, h = bh & 15;
  __shared__ __align__(16) bf16 t[64][72];
  const int tid = threadIdx.x;
  for (int c = tid; c < 512; c += 256) {
    int s = c >> 3, off = (c & 7) * 8;
    *(uint4*)&t[s][off] =
        *(const uint4*)&vsrc[(size_t)(b * NSK + st + s) * 2048 + 1024 + h * NDH + off];
  }
  __syncthreads();
  for (int c = tid; c < 512; c += 256) {
    int d = c >> 3, s0 = (c & 7) * 8;
    union { uint4 u; bf16 h[8]; } o;
#pragma unroll
    for (int i = 0; i < 8; ++i) o.h[i] = t[s0 + i][d];
    *(uint4*)&vT[((size_t)(bh * NDH + d)) * NSK + st + s0] = o.u;
  }
}

// ---------------- proj_gemm: KV (blocks 0..511) + Q (blocks 512..767), 16 waves/CU ----
// Both parts: 128x256 block, 8 waves (2M x 4N, 64x64 out each), BK=32, TRIPLE-buffered
// LDS (72 KB -> 2 blocks/CU), stage AFTER ds_reads, counted vmcnt(3), trailing
// lgkm0+barrier, granule-XOR swizzle, per-part XCD swizzle. As KV blocks drain,
// Q blocks backfill -> the two GEMMs overlap on the machine.
// KV epilogue: col<1024 -> (acc+bk)*LOG2E else acc+bv.  Q epilogue: (acc+bq)/32.
__global__ __launch_bounds__(512, 4) void proj_gemm(
    const bf16* __restrict__ Qb, const bf16* __restrict__ Kb,
    const bf16* __restrict__ Wqt, const bf16* __restrict__ Wkvt,
    const float* __restrict__ bq_, const float* __restrict__ bk_,
    const float* __restrict__ bv_,
    bf16* __restrict__ qout, bf16* __restrict__ kvout) {
  constexpr int NT = 32;                 // K = 1024 = 32 x 32
  __shared__ __align__(16) bf16 Asl[3][128 * 32];
  __shared__ __align__(16) bf16 Bsl[3][256 * 32];

  const int tid = threadIdx.x;
  const bool isQ = (blockIdx.x >= 512);
  const bf16* Ab; const bf16* Bt; bf16* Cb;
  int bcol, brow, Nout;
  if (!isQ) {
    const int f = blockIdx.x;
    const int xi = (f & 7) * 64 + (f >> 3);       // 512 blocks -> bijective
    bcol = (xi & 7) * 256; brow = (xi >> 3) * 128;
    Ab = Kb; Bt = Wkvt; Cb = kvout; Nout = 2048;
  } else {
    const int f = blockIdx.x - 512;
    const int xi = (f & 7) * 32 + (f >> 3);       // 256 blocks -> bijective
    bcol = (xi & 3) * 256; brow = (xi >> 2) * 128;
    Ab = Qb; Bt = Wqt; Cb = qout; Nout = 1024;
  }

  const int w = tid >> 6, lane = tid & 63;
  const int wm = w >> 2, wn = w & 3;              // 2M x 4N waves
  const int lr = lane & 15, l4 = lane >> 4;
  const int rgrp = l4 * 4;
  const int gph = (l4 ^ ((lr >> 1) & 3)) * 8;     // read-side swizzled granule

  // staging: 512 threads cover 128 rows x 4 granules per round.
  // LDS(row,g) = global(row, g ^ ((row>>1)&3)).
  const int srow = tid >> 2;                      // 0..127
  const int gsrc = (tid & 3) ^ ((tid >> 3) & 3);
  const bf16* Ag = Ab + (size_t)(brow + srow) * 1024 + gsrc * 8;
  const bf16* Bg = Bt + (size_t)(bcol + srow) * 1024 + gsrc * 8;
  const int ldo = srow * 32 + (tid & 3) * 8;

  auto stage = [&](int d, int kt) {   // 1 A round + 2 B rounds = 3 loads/thread
    async_load16(Ag + kt * 32, &Asl[d][ldo]);
#pragma unroll
    for (int r = 0; r < 2; ++r)
      async_load16(Bg + (size_t)r * (128 * 1024) + kt * 32, &Bsl[d][r * 4096 + ldo]);
  };

  f32x4 acc[4][4] = {};

  stage(0, 0);
  stage(1, 1);
  asm volatile("s_waitcnt vmcnt(3)" ::: "memory");   // tile 0 landed
  __builtin_amdgcn_s_barrier();

  int cur = 0, st2 = 2;
  for (int t = 0; t < NT; ++t) {
    bf16x8 af[4], bfr[4];
#pragma unroll
    for (int i = 0; i < 4; ++i)
      af[i] = *(const bf16x8*)&Asl[cur][(wm * 64 + i * 16 + lr) * 32 + gph];
#pragma unroll
    for (int n = 0; n < 4; ++n)
      bfr[n] = *(const bf16x8*)&Bsl[cur][(wn * 64 + n * 16 + lr) * 32 + gph];
    if (t + 2 < NT) stage(st2, t + 2);   // buffer last read at t-1 (pinned)
    __builtin_amdgcn_s_setprio(1);
#pragma unroll
    for (int i = 0; i < 4; ++i)
#pragma unroll
      for (int n = 0; n < 4; ++n)
        acc[i][n] = __builtin_amdgcn_mfma_f32_16x16x32_bf16(af[i], bfr[n], acc[i][n], 0, 0, 0);
    __builtin_amdgcn_s_setprio(0);
    if (t + 2 < NT)      asm volatile("s_waitcnt vmcnt(3)" ::: "memory");
    else if (t + 1 < NT) asm volatile("s_waitcnt vmcnt(0)" ::: "memory");
    asm volatile("s_waitcnt lgkmcnt(0)" ::: "memory");
    __builtin_amdgcn_s_barrier();
    cur = (cur == 2) ? 0 : cur + 1;
    st2 = (st2 == 2) ? 0 : st2 + 1;
  }

  // ---------------- epilogue ----------------
  const bool isV = (!isQ) && (bcol >= 1024);
#pragma unroll
  for (int m = 0; m < 4; ++m) {
#pragma unroll
    for (int n = 0; n < 4; ++n) {
      const int col = bcol + wn * 64 + n * 16 + lr;
      float bv, sc;
      if (isQ)      { bv = bq_[col];        sc = 0.03125f; }
      else if (isV) { bv = bv_[col - 1024]; sc = 1.0f; }
      else          { bv = bk_[col];        sc = LOG2E; }
#pragma unroll
      for (int r = 0; r < 4; ++r) {
        const int row = brow + wm * 64 + m * 16 + rgrp + r;
        Cb[(size_t)row * Nout + col] = (bf16)((acc[m][n][r] + bv) * sc);
      }
    }
  }
}

// ---------------- gemm3b: Wo GEMM (bf16 A, R10-proven) ----------------
// 128 x 128 block, 4 waves (2x2), BK=32, TRIPLE-buffered LDS, one barrier + counted
// vmcnt per K-tile, 2-tile-deep prefetch (stage AFTER ds_reads), granule-XOR swizzle.
// Cb = bf16(Res + relu(acc+bias)).
__global__ __launch_bounds__(256, 2) void gemm_wo(
    const bf16* __restrict__ Ab, const bf16* __restrict__ Bt,
    const float* __restrict__ bias,
    bf16* __restrict__ Cb, const bf16* __restrict__ Resb) {
  constexpr int NT = 32;
  __shared__ __align__(16) bf16 Asl[3][128 * 32];
  __shared__ __align__(16) bf16 Bsl[3][128 * 32];

  const int tid = threadIdx.x;
  const int flat = blockIdx.x;
  const int xi = (flat & 7) * 64 + (flat >> 3);
  const int bcol = (xi & 7) * 128;
  const int brow = (xi >> 3) * 128;

  const int w = tid >> 6, lane = tid & 63;
  const int wm = w >> 1, wn = w & 1;
  const int lr = lane & 15, l4 = lane >> 4;
  const int rgrp = l4 * 4;
  const int gph = (l4 ^ ((lr >> 1) & 3)) * 8;

  const int srow = tid >> 2;
  const int gsrc = (tid & 3) ^ ((tid >> 3) & 3);
  const bf16* Ag = Ab + (size_t)(brow + srow) * 1024 + gsrc * 8;
  const bf16* Bg = Bt + (size_t)(bcol + srow) * 1024 + gsrc * 8;
  const int ldo = srow * 32 + (tid & 3) * 8;

  auto stage = [&](int d, int kt) {
#pragma unroll
    for (int r = 0; r < 2; ++r)
      async_load16(Ag + (size_t)r * (64 * 1024) + kt * 32, &Asl[d][r * 2048 + ldo]);
#pragma unroll
    for (int r = 0; r < 2; ++r)
      async_load16(Bg + (size_t)r * (64 * 1024) + kt * 32, &Bsl[d][r * 2048 + ldo]);
  };

  f32x4 acc[4][4] = {};

  stage(0, 0);
  stage(1, 1);
  asm volatile("s_waitcnt vmcnt(4)" ::: "memory");
  __builtin_amdgcn_s_barrier();

  int cur = 0, st2 = 2;
  for (int t = 0; t < NT; ++t) {
    bf16x8 af[4], bfr[4];
#pragma unroll
    for (int i = 0; i < 4; ++i)
      af[i] = *(const bf16x8*)&Asl[cur][(wm * 64 + i * 16 + lr) * 32 + gph];
#pragma unroll
    for (int n = 0; n < 4; ++n)
      bfr[n] = *(const bf16x8*)&Bsl[cur][(wn * 64 + n * 16 + lr) * 32 + gph];
    if (t + 2 < NT) stage(st2, t + 2);
    __builtin_amdgcn_s_setprio(1);
#pragma unroll
    for (int i = 0; i < 4; ++i)
#pragma unroll
      for (int n = 0; n < 4; ++n)
        acc[i][n] = __builtin_amdgcn_mfma_f32_16x16x32_bf16(af[i], bfr[n], acc[i][n], 0, 0, 0);
    __builtin_amdgcn_s_setprio(0);
    if (t + 2 < NT)      asm volatile("s_waitcnt vmcnt(4)" ::: "memory");
    else if (t + 1 < NT) asm volatile("s_waitcnt vmcnt(0)" ::: "memory");
    asm volatile("s_waitcnt lgkmcnt(0)" ::: "memory");
    __builtin_amdgcn_s_barrier();
    cur = (cur == 2) ? 0 : cur + 1;
    st2 = (st2 == 2) ? 0 : st2 + 1;
  }

#pragma unroll
  for (int m = 0; m < 4; ++m) {
#pragma unroll
    for (int n = 0; n < 4; ++n) {
      const int col = bcol + wn * 64 + n * 16 + lr;
      const float bv = bias[col];
#pragma unroll
      for (int r = 0; r < 4; ++r) {
        const int row = brow + wm * 64 + m * 16 + rgrp + r;
        float v = acc[m][n][r] + bv;
        float res = (float)Resb[(size_t)row * 1024 + col];
        Cb[(size_t)row * 1024 + col] = (bf16)(res + (v > 0.f ? v : 0.f));
      }
    }
  }
}

// ---------------- fused attention: 8 waves x 32 q, 32x32 MFMA, in-register P ----------
// 1-D grid of 512 blocks, XCD-remapped so all 4 q-blocks of one (b,h) share an XCD
// (K/V panels become L2-resident; verified FETCH 73.8 -> 24.6 MB).
__global__ __launch_bounds__(512, 4) void attn_kernel(
    const bf16* __restrict__ qb, const bf16* __restrict__ kvb,
    const bf16* __restrict__ vT, bf16* __restrict__ attnout) {
  const int bid = blockIdx.x;
  const int bh = (bid & 7) * 16 + ((bid >> 3) & 15);
  const int qi = bid >> 7;
  const int b = bh >> 4, h = bh & 15;
  const int tid = threadIdx.x, w = tid >> 6, lane = tid & 63;
  const int l31 = lane & 31;
  const int l1 = lane >> 5;
  const int q0w = qi * 256 + w * 32;

  __shared__ __align__(16) bf16 Kl[2][64 * 64];
  __shared__ __align__(16) bf16 Vl[2][64 * 64];

  const int srow = tid >> 3;
  const int sgran = tid & 7;
  const int gsw = sgran ^ (srow & 7);
  const int ldst = srow * 64 + sgran * 8;
  const int rg = l31 & 7;

  const bf16* kbase = kvb + (size_t)(b * NSK) * 2048 + h * NDH;
  const bf16* vbase = vT + (size_t)(bh * NDH) * NSK;

  bf16x8 qf[4];
#pragma unroll
  for (int kd = 0; kd < 4; ++kd)
    qf[kd] = *(const bf16x8*)&qb[(size_t)(b * NSQ + q0w + l31) * ND +
                                 h * NDH + kd * 16 + l1 * 8];

  f32x16 oacc0 = {}, oacc1 = {}, lacc = {};
  bf16x8 ones;
#pragma unroll
  for (int i = 0; i < 8; ++i) ones[i] = (bf16)1.0f;

  auto stage = [&](int bi, int kt) {
    async_load16(kbase + (size_t)(kt + srow) * 2048 + gsw * 8, &Kl[bi][ldst]);
    async_load16(vbase + (size_t)srow * NSK + kt + gsw * 8, &Vl[bi][ldst]);
  };

  stage(0, 0);

  for (int t = 0; t < 16; ++t) {
    const int bi = t & 1;
    asm volatile("s_waitcnt vmcnt(0)" ::: "memory");
    __syncthreads();
    if (t < 15) stage(bi ^ 1, (t + 1) * 64);

    uint32 W[2][4][2];
#pragma unroll
    for (int n = 0; n < 2; ++n) {
      f32x16 s = {};
      __builtin_amdgcn_s_setprio(1);
#pragma unroll
      for (int kd = 0; kd < 4; ++kd) {
        bf16x8 kf = *(const bf16x8*)&Kl[bi][(n * 32 + l31) * 64 + (((kd * 2 + l1) ^ rg) * 8)];
        s = __builtin_amdgcn_mfma_f32_32x32x16_bf16(kf, qf[kd], s, 0, 0, 0);
      }
      __builtin_amdgcn_s_setprio(0);
#pragma unroll
      for (int r2 = 0; r2 < 4; ++r2)
#pragma unroll
        for (int p = 0; p < 2; ++p) {
          float elo = __builtin_amdgcn_exp2f(s[r2 * 4 + 2 * p]);
          float ehi = __builtin_amdgcn_exp2f(s[r2 * 4 + 2 * p + 1]);
          uint32 wd;
          asm("v_cvt_pk_bf16_f32 %0, %1, %2" : "=v"(wd) : "v"(elo), "v"(ehi));
          W[n][r2][p] = wd;
        }
    }
    __builtin_amdgcn_s_setprio(1);
#pragma unroll
    for (int kc = 0; kc < 4; ++kc) {
      uint32 x0 = W[kc >> 1][(kc & 1) * 2][0], y0 = W[kc >> 1][(kc & 1) * 2 + 1][0];
      uint32 x1 = W[kc >> 1][(kc & 1) * 2][1], y1 = W[kc >> 1][(kc & 1) * 2 + 1][1];
      permswap(x0, y0);
      permswap(x1, y1);
      union { uint32 u[4]; bf16x8 v; } cvt;
      cvt.u[0] = x0; cvt.u[1] = x1; cvt.u[2] = y0; cvt.u[3] = y1;
      bf16x8 pa = cvt.v;
      bf16x8 vf0 = *(const bf16x8*)&Vl[bi][(l31) * 64 + (((kc * 2 + l1) ^ rg) * 8)];
      bf16x8 vf1 = *(const bf16x8*)&Vl[bi][(32 + l31) * 64 + (((kc * 2 + l1) ^ rg) * 8)];
      oacc0 = __builtin_amdgcn_mfma_f32_32x32x16_bf16(pa, vf0, oacc0, 0, 0, 0);
      oacc1 = __builtin_amdgcn_mfma_f32_32x32x16_bf16(pa, vf1, oacc1, 0, 0, 0);
      lacc = __builtin_amdgcn_mfma_f32_32x32x16_bf16(pa, ones, lacc, 0, 0, 0);
    }
    __builtin_amdgcn_s_setprio(0);
  }

  float inv[16];
#pragma unroll
  for (int r = 0; r < 16; ++r) inv[r] = 1.0f / lacc[r];
#pragma unroll
  for (int r = 0; r < 16; ++r) {
    const int row = q0w + (r & 3) + 8 * (r >> 2) + 4 * l1;
    attnout[(size_t)(b * NSQ + row) * ND + h * NDH + l31] = (bf16)(oacc0[r] * inv[r]);
    attnout[(size_t)(b * NSQ + row) * ND + h * NDH + 32 + l31] = (bf16)(oacc1[r] * inv[r]);
  }
}

// ---------------- LayerNorm over bf16 input ----------------
template <bool RES, bool OUTF>
__global__ __launch_bounds__(256) void ln_kernel(
    const bf16* __restrict__ x, const bf16* __restrict__ rq, float rscale,
    const float* __restrict__ g, const float* __restrict__ be,
    bf16* __restrict__ yb, float* __restrict__ yf) {
  __shared__ float sm[4];
  const int row = blockIdx.x, tid = threadIdx.x;
  const size_t base = (size_t)row * ND + tid * 4;
  union { uint2 u; bf16 h[4]; } xv;
  xv.u = *(const uint2*)(x + base);
  float v0 = (float)xv.h[0], v1 = (float)xv.h[1], v2 = (float)xv.h[2], v3 = (float)xv.h[3];
  if (RES) {
    union { uint2 u; bf16 h[4]; } q;
    q.u = *(const uint2*)(rq + base);
    v0 += rscale * (float)q.h[0]; v1 += rscale * (float)q.h[1];
    v2 += rscale * (float)q.h[2]; v3 += rscale * (float)q.h[3];
  }
  float s = v0 + v1 + v2 + v3;
#pragma unroll
  for (int off = 32; off > 0; off >>= 1) s += __shfl_down(s, off, 64);
  if ((tid & 63) == 0) sm[tid >> 6] = s;
  __syncthreads();
  const float mean = (sm[0] + sm[1] + sm[2] + sm[3]) * (1.0f / ND);
  __syncthreads();
  const float d0 = v0 - mean, d1 = v1 - mean, d2 = v2 - mean, d3 = v3 - mean;
  float sq = d0 * d0 + d1 * d1 + d2 * d2 + d3 * d3;
#pragma unroll
  for (int off = 32; off > 0; off >>= 1) sq += __shfl_down(sq, off, 64);
  if ((tid & 63) == 0) sm[tid >> 6] = sq;
  __syncthreads();
  const float var = (sm[0] + sm[1] + sm[2] + sm[3]) * (1.0f / ND);
  const float rs = rsqrtf(var + 1e-5f);
  float4 gv = *(const float4*)(g + tid * 4);
  float4 bv = *(const float4*)(be + tid * 4);
  const float y0 = d0 * rs * gv.x + bv.x;
  const float y1 = d1 * rs * gv.y + bv.y;
  const float y2 = d2 * rs * gv.z + bv.z;
  const float y3 = d3 * rs * gv.w + bv.w;
  if (OUTF) {
    *(float4*)(yf + base) = make_float4(y0, y1, y2, y3);
  } else {
    union { uint2 u; bf16 h[4]; } o;
    o.h[0] = (bf16)y0; o.h[1] = (bf16)y1; o.h[2] = (bf16)y2; o.h[3] = (bf16)y3;
    *(uint2*)(yb + base) = o.u;
  }
}

extern "C" void kernel_launch(void* const* d_in, const int* in_sizes, int n_in,
                              void* d_out, int out_size, void* d_ws, size_t ws_size,
                              hipStream_t stream) {
  const float* Q  = (const float*)d_in[0];
  const float* K  = (const float*)d_in[1];
  const float* Wq = (const float*)d_in[2];
  const float* bq = (const float*)d_in[3];
  const float* Wk = (const float*)d_in[4];
  const float* bk = (const float*)d_in[5];
  const float* Wv = (const float*)d_in[6];
  const float* bv = (const float*)d_in[7];
  const float* Wo = (const float*)d_in[8];
  const float* bo = (const float*)d_in[9];
  const float* g0 = (const float*)d_in[10];
  const float* b0 = (const float*)d_in[11];
  const float* g1 = (const float*)d_in[12];
  const float* b1 = (const float*)d_in[13];
  float* out = (float*)d_out;

  char* ws = (char*)d_ws;
  const size_t MB = 1024 * 1024;
  bf16* Qb    = (bf16*)(ws + 0);          // 16MB
  bf16* Kb    = (bf16*)(ws + 16 * MB);    // 16MB
  bf16* Wqt   = (bf16*)(ws + 32 * MB);    // 2MB
  bf16* Wkvt  = (bf16*)(ws + 34 * MB);    // 4MB ([2048][1024])
  bf16* Wot   = (bf16*)(ws + 38 * MB);    // 2MB
  bf16* qb    = (bf16*)(ws + 40 * MB);    // 16MB
  bf16* kvb   = (bf16*)(ws + 56 * MB);    // 32MB ([8192][2048]: k | v)
  bf16* vT    = (bf16*)(ws + 88 * MB);    // 16MB
  bf16* attnb = (bf16*)(ws + 104 * MB);   // 16MB
  bf16* h0b   = (bf16*)(ws + 56 * MB);    // reuse kvb (dead after attn)
  bf16* out1b = (bf16*)(ws + 0);          // reuse Qb (dead after proj)

  // 1. prep: weight transpose+cvt (z<4) and Q/K->bf16 (z=4,5) in one dispatch
  prep_kernel<<<dim3(16, 16, 6), 256, 0, stream>>>(
      Wq, Wk, Wv, Wo, Wqt, Wkvt, Wkvt + 1024 * 1024, Wot, Q, K, Qb, Kb);
  // 2. fused projections: KV (512 blocks) + Q (256 blocks) overlap on the machine
  proj_gemm<<<768, 512, 0, stream>>>(Qb, Kb, Wqt, Wkvt, bq, bk, bv, qb, kvb);
  // 3. v -> vT per head
  transpose_v<<<dim3(16, 128), 256, 0, stream>>>(kvb, vT);
  // 4. attention (normalized bf16 out, XCD-remapped grid)
  attn_kernel<<<512, 512, 0, stream>>>(qb, kvb, vT, attnb);
  // 5. h0 = LN(32*qb + attn)
  ln_kernel<true, false><<<8192, 256, 0, stream>>>(attnb, qb, 32.0f, g0, b0, h0b, nullptr);
  // 6. out1 = h0 + relu(h0 @ Wo + bo)
  gemm_wo<<<512, 256, 0, stream>>>(h0b, Wot, bo, out1b, h0b);
  // 7. out = LN(out1)
  ln_kernel<false, true><<<8192, 256, 0, stream>>>(out1b, nullptr, 0.f, g1, b1, nullptr, out);
}

// Round 21
// 171.169 us; speedup vs baseline: 1.0467x; 1.0244x over previous
//
#include <hip/hip_runtime.h>
#include <hip/hip_bf16.h>
#include <stdint.h>

// Problem dims
#define NB 8
#define NSQ 1024
#define NSK 1024
#define ND 1024
#define NH 16
#define NDH 64
#define NM (NB * NSQ)   // 8192 rows
#define LOG2E 1.4426950408889634f

typedef __bf16 bf16;
typedef __bf16 bf16x8 __attribute__((ext_vector_type(8)));
typedef float f32x4 __attribute__((ext_vector_type(4)));
typedef float f32x16 __attribute__((ext_vector_type(16)));
typedef unsigned int uint32;

// ---------------- async global->LDS (16B per lane) ----------------
__device__ __forceinline__ void async_load16(const void* g, void* l) {
  __builtin_amdgcn_global_load_lds(
      (__attribute__((address_space(1))) void*)g,
      (__attribute__((address_space(3))) void*)l, 16, 0, 0);
}

// half-swap: x' = {x.lo, y.lo}, y' = {x.hi, y.hi}
__device__ __forceinline__ void permswap(uint32& x, uint32& y) {
#if __has_builtin(__builtin_amdgcn_permlane32_swap)
  auto r = __builtin_amdgcn_permlane32_swap(x, y, false, false);
  x = r[0]; y = r[1];
#else
  asm volatile("v_permlane32_swap_b32 %0, %1" : "+v"(x), "+v"(y));
#endif
}

// ---------------- prep: 4x weight transpose+cvt (z<4) + Q/K cvt (z=4,5) ----------------
__global__ __launch_bounds__(256) void prep_kernel(
    const float* __restrict__ W0, const float* __restrict__ W1,
    const float* __restrict__ W2, const float* __restrict__ W3,
    bf16* __restrict__ O0, bf16* __restrict__ O1,
    bf16* __restrict__ O2, bf16* __restrict__ O3,
    const float* __restrict__ Qf, const float* __restrict__ Kf,
    bf16* __restrict__ Qb, bf16* __restrict__ Kb) {
  if (blockIdx.z >= 4) {
    const float* in = (blockIdx.z == 4) ? Qf : Kf;
    bf16* out = (blockIdx.z == 4) ? Qb : Kb;
    int base = (blockIdx.y * 16 + blockIdx.x) * 256 + threadIdx.x;  // 0..65535
    for (int i = base; i < 2097152; i += 65536) {
      float4 v = *(const float4*)(in + (size_t)i * 4);
      union { uint64_t u; bf16 h[4]; } o;
      o.h[0] = (bf16)v.x; o.h[1] = (bf16)v.y; o.h[2] = (bf16)v.z; o.h[3] = (bf16)v.w;
      *(uint64_t*)(out + (size_t)i * 4) = o.u;
    }
    return;
  }
  const float* W; bf16* Wt;
  switch (blockIdx.z) {
    case 0: W = W0; Wt = O0; break;
    case 1: W = W1; Wt = O1; break;
    case 2: W = W2; Wt = O2; break;
    default: W = W3; Wt = O3; break;
  }
  __shared__ float t[64][65];
  const int bc = blockIdx.x * 64;
  const int br = blockIdx.y * 64;
  const int tid = threadIdx.x;
  for (int c = tid; c < 1024; c += 256) {
    int r = c >> 4, off = (c & 15) * 4;
    float4 v = *(const float4*)&W[(size_t)(br + r) * 1024 + bc + off];
    t[r][off] = v.x; t[r][off + 1] = v.y; t[r][off + 2] = v.z; t[r][off + 3] = v.w;
  }
  __syncthreads();
  for (int c = tid; c < 512; c += 256) {
    int cc = c >> 3, rr = (c & 7) * 8;
    union { uint4 u; bf16 h[8]; } o;
#pragma unroll
    for (int i = 0; i < 8; ++i) o.h[i] = (bf16)t[rr + i][cc];
    *(uint4*)&Wt[(size_t)(bc + cc) * 1024 + br + rr] = o.u;
  }
}

// ---------------- gemm16w_kv: KV GEMM, V written directly in vT layout ----------------
// 128x256 block, 8 waves (2M x 4N, 64x64 out each), BK=32, TRIPLE-buffered LDS
// (72 KB raw smem, Asl/Bsl views; 2 blocks/CU = 16 waves/CU). Stage AFTER ds_reads,
// counted vmcnt(3), trailing lgkm0+barrier, granule-XOR swizzle, XCD swizzle.
// K blocks (bcol<1024): kvout[row*2048+col] = (acc+bk)*LOG2E  (row-major K half).
// V blocks: acc+bv staged TRANSPOSED into LDS [256 col][132 pad], then written
// coalesced to vT[(b*16+h)*64+d][s] -- transpose_v kernel eliminated.
__global__ __launch_bounds__(512, 4) void gemm16w_kv(
    const bf16* __restrict__ Ab, const bf16* __restrict__ Bt,
    const float* __restrict__ bk_, const float* __restrict__ bv_,
    bf16* __restrict__ kvout, bf16* __restrict__ vT) {
  constexpr int NT = 32;                 // K = 1024 = 32 x 32
  __shared__ __align__(16) char smem[73728];          // 72 KB
  bf16 (*Asl)[128 * 32] = (bf16(*)[128 * 32])smem;            // 3 x 8 KB
  bf16 (*Bsl)[256 * 32] = (bf16(*)[256 * 32])(smem + 24576);  // 3 x 16 KB
  bf16* Vt = (bf16*)smem;                             // epilogue view [256][132]

  const int tid = threadIdx.x;
  const int flat = blockIdx.x;
  const int xi = (flat & 7) * 64 + (flat >> 3);   // 512 blocks -> bijective
  const int bcol = (xi & 7) * 256;
  const int brow = (xi >> 3) * 128;

  const int w = tid >> 6, lane = tid & 63;
  const int wm = w >> 2, wn = w & 3;              // 2M x 4N waves
  const int lr = lane & 15, l4 = lane >> 4;
  const int rgrp = l4 * 4;
  const int gph = (l4 ^ ((lr >> 1) & 3)) * 8;     // read-side swizzled granule

  const int srow = tid >> 2;                      // 0..127
  const int gsrc = (tid & 3) ^ ((tid >> 3) & 3);
  const bf16* Ag = Ab + (size_t)(brow + srow) * 1024 + gsrc * 8;
  const bf16* Bg = Bt + (size_t)(bcol + srow) * 1024 + gsrc * 8;
  const int ldo = srow * 32 + (tid & 3) * 8;

  auto stage = [&](int d, int kt) {   // 1 A round + 2 B rounds = 3 loads/thread
    async_load16(Ag + kt * 32, &Asl[d][ldo]);
#pragma unroll
    for (int r = 0; r < 2; ++r)
      async_load16(Bg + (size_t)r * (128 * 1024) + kt * 32, &Bsl[d][r * 4096 + ldo]);
  };

  f32x4 acc[4][4] = {};

  stage(0, 0);
  stage(1, 1);
  asm volatile("s_waitcnt vmcnt(3)" ::: "memory");   // tile 0 landed
  __builtin_amdgcn_s_barrier();

  int cur = 0, st2 = 2;
  for (int t = 0; t < NT; ++t) {
    bf16x8 af[4], bfr[4];
#pragma unroll
    for (int i = 0; i < 4; ++i)
      af[i] = *(const bf16x8*)&Asl[cur][(wm * 64 + i * 16 + lr) * 32 + gph];
#pragma unroll
    for (int n = 0; n < 4; ++n)
      bfr[n] = *(const bf16x8*)&Bsl[cur][(wn * 64 + n * 16 + lr) * 32 + gph];
    if (t + 2 < NT) stage(st2, t + 2);   // buffer last read at t-1 (pinned)
    __builtin_amdgcn_s_setprio(1);
#pragma unroll
    for (int i = 0; i < 4; ++i)
#pragma unroll
      for (int n = 0; n < 4; ++n)
        acc[i][n] = __builtin_amdgcn_mfma_f32_16x16x32_bf16(af[i], bfr[n], acc[i][n], 0, 0, 0);
    __builtin_amdgcn_s_setprio(0);
    if (t + 2 < NT)      asm volatile("s_waitcnt vmcnt(3)" ::: "memory");
    else if (t + 1 < NT) asm volatile("s_waitcnt vmcnt(0)" ::: "memory");
    asm volatile("s_waitcnt lgkmcnt(0)" ::: "memory");
    __builtin_amdgcn_s_barrier();
    cur = (cur == 2) ? 0 : cur + 1;
    st2 = (st2 == 2) ? 0 : st2 + 1;
  }
  // after the final barrier all LDS reads are drained -> smem reusable

  if (bcol < 1024) {
    // ---------------- K epilogue (row-major into kv K-half) ----------------
#pragma unroll
    for (int m = 0; m < 4; ++m) {
#pragma unroll
      for (int n = 0; n < 4; ++n) {
        const int col = bcol + wn * 64 + n * 16 + lr;
        const float bvv = bk_[col];
#pragma unroll
        for (int r = 0; r < 4; ++r) {
          const int row = brow + wm * 64 + m * 16 + rgrp + r;
          kvout[(size_t)row * 2048 + col] = (bf16)((acc[m][n][r] + bvv) * LOG2E);
        }
      }
    }
  } else {
    // ---------------- V epilogue: transpose via LDS, write vT ----------------
#pragma unroll
    for (int m = 0; m < 4; ++m) {
#pragma unroll
      for (int n = 0; n < 4; ++n) {
        const int cl = wn * 64 + n * 16 + lr;          // col_local 0..255
        const float bvv = bv_[(bcol - 1024) + cl];
        const int rl = wm * 64 + m * 16 + rgrp;        // row_local base
#pragma unroll
        for (int r = 0; r < 4; ++r)
          Vt[cl * 132 + rl + r] = (bf16)(acc[m][n][r] + bvv);
      }
    }
    asm volatile("s_waitcnt lgkmcnt(0)" ::: "memory");
    __builtin_amdgcn_s_barrier();
    // write-out: 512 threads x half-row (64 s = 128B contiguous) each
    const int orow = tid >> 1;                         // col_local 0..255
    const int half = tid & 1;
    const int colV = (bcol - 1024) + orow;
    const int h = colV >> 6, d = colV & 63;
    const int bb = brow >> 10;
    const int s0 = (brow & 1023) + half * 64;
    bf16* dst = vT + ((size_t)((bb * 16 + h) * 64 + d)) * NSK + s0;
    const bf16* src = &Vt[orow * 132 + half * 64];
#pragma unroll
    for (int c = 0; c < 8; ++c)
      *(uint4*)(dst + c * 8) = *(const uint4*)(src + c * 8);
  }
}

// ---------------- gemm3b: q / Wo GEMM (bf16 A, R10-proven) ----------------
// 128 x 128 block, 4 waves (2x2), BK=32, TRIPLE-buffered LDS, one barrier + counted
// vmcnt per K-tile, 2-tile-deep prefetch (stage AFTER ds_reads), granule-XOR swizzle.
// MODE 0: Cb = bf16((acc+bias)*scale).  MODE 1: Cb = bf16(Res + relu(acc+bias)).
template <int MODE>
__global__ __launch_bounds__(256, 2) void gemm3b(
    const bf16* __restrict__ Ab, const bf16* __restrict__ Bt,
    const float* __restrict__ bias,
    bf16* __restrict__ Cb, const bf16* __restrict__ Resb, float scale) {
  constexpr int NT = 32;
  __shared__ __align__(16) bf16 Asl[3][128 * 32];
  __shared__ __align__(16) bf16 Bsl[3][128 * 32];

  const int tid = threadIdx.x;
  const int flat = blockIdx.x;
  const int xi = (flat & 7) * 64 + (flat >> 3);
  const int bcol = (xi & 7) * 128;
  const int brow = (xi >> 3) * 128;

  const int w = tid >> 6, lane = tid & 63;
  const int wm = w >> 1, wn = w & 1;
  const int lr = lane & 15, l4 = lane >> 4;
  const int rgrp = l4 * 4;
  const int gph = (l4 ^ ((lr >> 1) & 3)) * 8;

  const int srow = tid >> 2;
  const int gsrc = (tid & 3) ^ ((tid >> 3) & 3);
  const bf16* Ag = Ab + (size_t)(brow + srow) * 1024 + gsrc * 8;
  const bf16* Bg = Bt + (size_t)(bcol + srow) * 1024 + gsrc * 8;
  const int ldo = srow * 32 + (tid & 3) * 8;

  auto stage = [&](int d, int kt) {
#pragma unroll
    for (int r = 0; r < 2; ++r)
      async_load16(Ag + (size_t)r * (64 * 1024) + kt * 32, &Asl[d][r * 2048 + ldo]);
#pragma unroll
    for (int r = 0; r < 2; ++r)
      async_load16(Bg + (size_t)r * (64 * 1024) + kt * 32, &Bsl[d][r * 2048 + ldo]);
  };

  f32x4 acc[4][4] = {};

  stage(0, 0);
  stage(1, 1);
  asm volatile("s_waitcnt vmcnt(4)" ::: "memory");
  __builtin_amdgcn_s_barrier();

  int cur = 0, st2 = 2;
  for (int t = 0; t < NT; ++t) {
    bf16x8 af[4], bfr[4];
#pragma unroll
    for (int i = 0; i < 4; ++i)
      af[i] = *(const bf16x8*)&Asl[cur][(wm * 64 + i * 16 + lr) * 32 + gph];
#pragma unroll
    for (int n = 0; n < 4; ++n)
      bfr[n] = *(const bf16x8*)&Bsl[cur][(wn * 64 + n * 16 + lr) * 32 + gph];
    if (t + 2 < NT) stage(st2, t + 2);
    __builtin_amdgcn_s_setprio(1);
#pragma unroll
    for (int i = 0; i < 4; ++i)
#pragma unroll
      for (int n = 0; n < 4; ++n)
        acc[i][n] = __builtin_amdgcn_mfma_f32_16x16x32_bf16(af[i], bfr[n], acc[i][n], 0, 0, 0);
    __builtin_amdgcn_s_setprio(0);
    if (t + 2 < NT)      asm volatile("s_waitcnt vmcnt(4)" ::: "memory");
    else if (t + 1 < NT) asm volatile("s_waitcnt vmcnt(0)" ::: "memory");
    asm volatile("s_waitcnt lgkmcnt(0)" ::: "memory");
    __builtin_amdgcn_s_barrier();
    cur = (cur == 2) ? 0 : cur + 1;
    st2 = (st2 == 2) ? 0 : st2 + 1;
  }

#pragma unroll
  for (int m = 0; m < 4; ++m) {
#pragma unroll
    for (int n = 0; n < 4; ++n) {
      const int col = bcol + wn * 64 + n * 16 + lr;
      const float bv = bias[col];
#pragma unroll
      for (int r = 0; r < 4; ++r) {
        const int row = brow + wm * 64 + m * 16 + rgrp + r;
        float v = acc[m][n][r] + bv;
        if (MODE == 1) {
          float res = (float)Resb[(size_t)row * 1024 + col];
          Cb[(size_t)row * 1024 + col] = (bf16)(res + (v > 0.f ? v : 0.f));
        } else {
          Cb[(size_t)row * 1024 + col] = (bf16)(v * scale);
        }
      }
    }
  }
}

// ---------------- fused attention: 8 waves x 32 q, 32x32 MFMA, in-register P ----------
// 1-D grid of 512 blocks, XCD-remapped so all 4 q-blocks of one (b,h) share an XCD
// (K/V panels L2-resident; verified FETCH 73.8 -> 24.6 MB).
__global__ __launch_bounds__(512, 4) void attn_kernel(
    const bf16* __restrict__ qb, const bf16* __restrict__ kvb,
    const bf16* __restrict__ vT, bf16* __restrict__ attnout) {
  const int bid = blockIdx.x;
  const int bh = (bid & 7) * 16 + ((bid >> 3) & 15);
  const int qi = bid >> 7;
  const int b = bh >> 4, h = bh & 15;
  const int tid = threadIdx.x, w = tid >> 6, lane = tid & 63;
  const int l31 = lane & 31;
  const int l1 = lane >> 5;
  const int q0w = qi * 256 + w * 32;

  __shared__ __align__(16) bf16 Kl[2][64 * 64];
  __shared__ __align__(16) bf16 Vl[2][64 * 64];

  const int srow = tid >> 3;
  const int sgran = tid & 7;
  const int gsw = sgran ^ (srow & 7);
  const int ldst = srow * 64 + sgran * 8;
  const int rg = l31 & 7;

  const bf16* kbase = kvb + (size_t)(b * NSK) * 2048 + h * NDH;
  const bf16* vbase = vT + (size_t)(bh * NDH) * NSK;

  bf16x8 qf[4];
#pragma unroll
  for (int kd = 0; kd < 4; ++kd)
    qf[kd] = *(const bf16x8*)&qb[(size_t)(b * NSQ + q0w + l31) * ND +
                                 h * NDH + kd * 16 + l1 * 8];

  f32x16 oacc0 = {}, oacc1 = {}, lacc = {};
  bf16x8 ones;
#pragma unroll
  for (int i = 0; i < 8; ++i) ones[i] = (bf16)1.0f;

  auto stage = [&](int bi, int kt) {
    async_load16(kbase + (size_t)(kt + srow) * 2048 + gsw * 8, &Kl[bi][ldst]);
    async_load16(vbase + (size_t)srow * NSK + kt + gsw * 8, &Vl[bi][ldst]);
  };

  stage(0, 0);

  for (int t = 0; t < 16; ++t) {
    const int bi = t & 1;
    asm volatile("s_waitcnt vmcnt(0)" ::: "memory");
    __syncthreads();
    if (t < 15) stage(bi ^ 1, (t + 1) * 64);

    uint32 W[2][4][2];
#pragma unroll
    for (int n = 0; n < 2; ++n) {
      f32x16 s = {};
      __builtin_amdgcn_s_setprio(1);
#pragma unroll
      for (int kd = 0; kd < 4; ++kd) {
        bf16x8 kf = *(const bf16x8*)&Kl[bi][(n * 32 + l31) * 64 + (((kd * 2 + l1) ^ rg) * 8)];
        s = __builtin_amdgcn_mfma_f32_32x32x16_bf16(kf, qf[kd], s, 0, 0, 0);
      }
      __builtin_amdgcn_s_setprio(0);
#pragma unroll
      for (int r2 = 0; r2 < 4; ++r2)
#pragma unroll
        for (int p = 0; p < 2; ++p) {
          float elo = __builtin_amdgcn_exp2f(s[r2 * 4 + 2 * p]);
          float ehi = __builtin_amdgcn_exp2f(s[r2 * 4 + 2 * p + 1]);
          uint32 wd;
          asm("v_cvt_pk_bf16_f32 %0, %1, %2" : "=v"(wd) : "v"(elo), "v"(ehi));
          W[n][r2][p] = wd;
        }
    }
    __builtin_amdgcn_s_setprio(1);
#pragma unroll
    for (int kc = 0; kc < 4; ++kc) {
      uint32 x0 = W[kc >> 1][(kc & 1) * 2][0], y0 = W[kc >> 1][(kc & 1) * 2 + 1][0];
      uint32 x1 = W[kc >> 1][(kc & 1) * 2][1], y1 = W[kc >> 1][(kc & 1) * 2 + 1][1];
      permswap(x0, y0);
      permswap(x1, y1);
      union { uint32 u[4]; bf16x8 v; } cvt;
      cvt.u[0] = x0; cvt.u[1] = x1; cvt.u[2] = y0; cvt.u[3] = y1;
      bf16x8 pa = cvt.v;
      bf16x8 vf0 = *(const bf16x8*)&Vl[bi][(l31) * 64 + (((kc * 2 + l1) ^ rg) * 8)];
      bf16x8 vf1 = *(const bf16x8*)&Vl[bi][(32 + l31) * 64 + (((kc * 2 + l1) ^ rg) * 8)];
      oacc0 = __builtin_amdgcn_mfma_f32_32x32x16_bf16(pa, vf0, oacc0, 0, 0, 0);
      oacc1 = __builtin_amdgcn_mfma_f32_32x32x16_bf16(pa, vf1, oacc1, 0, 0, 0);
      lacc = __builtin_amdgcn_mfma_f32_32x32x16_bf16(pa, ones, lacc, 0, 0, 0);
    }
    __builtin_amdgcn_s_setprio(0);
  }

  float inv[16];
#pragma unroll
  for (int r = 0; r < 16; ++r) inv[r] = 1.0f / lacc[r];
#pragma unroll
  for (int r = 0; r < 16; ++r) {
    const int row = q0w + (r & 3) + 8 * (r >> 2) + 4 * l1;
    attnout[(size_t)(b * NSQ + row) * ND + h * NDH + l31] = (bf16)(oacc0[r] * inv[r]);
    attnout[(size_t)(b * NSQ + row) * ND + h * NDH + 32 + l31] = (bf16)(oacc1[r] * inv[r]);
  }
}

// ---------------- LayerNorm over bf16 input ----------------
template <bool RES, bool OUTF>
__global__ __launch_bounds__(256) void ln_kernel(
    const bf16* __restrict__ x, const bf16* __restrict__ rq, float rscale,
    const float* __restrict__ g, const float* __restrict__ be,
    bf16* __restrict__ yb, float* __restrict__ yf) {
  __shared__ float sm[4];
  const int row = blockIdx.x, tid = threadIdx.x;
  const size_t base = (size_t)row * ND + tid * 4;
  union { uint2 u; bf16 h[4]; } xv;
  xv.u = *(const uint2*)(x + base);
  float v0 = (float)xv.h[0], v1 = (float)xv.h[1], v2 = (float)xv.h[2], v3 = (float)xv.h[3];
  if (RES) {
    union { uint2 u; bf16 h[4]; } q;
    q.u = *(const uint2*)(rq + base);
    v0 += rscale * (float)q.h[0]; v1 += rscale * (float)q.h[1];
    v2 += rscale * (float)q.h[2]; v3 += rscale * (float)q.h[3];
  }
  float s = v0 + v1 + v2 + v3;
#pragma unroll
  for (int off = 32; off > 0; off >>= 1) s += __shfl_down(s, off, 64);
  if ((tid & 63) == 0) sm[tid >> 6] = s;
  __syncthreads();
  const float mean = (sm[0] + sm[1] + sm[2] + sm[3]) * (1.0f / ND);
  __syncthreads();
  const float d0 = v0 - mean, d1 = v1 - mean, d2 = v2 - mean, d3 = v3 - mean;
  float sq = d0 * d0 + d1 * d1 + d2 * d2 + d3 * d3;
#pragma unroll
  for (int off = 32; off > 0; off >>= 1) sq += __shfl_down(sq, off, 64);
  if ((tid & 63) == 0) sm[tid >> 6] = sq;
  __syncthreads();
  const float var = (sm[0] + sm[1] + sm[2] + sm[3]) * (1.0f / ND);
  const float rs = rsqrtf(var + 1e-5f);
  float4 gv = *(const float4*)(g + tid * 4);
  float4 bv = *(const float4*)(be + tid * 4);
  const float y0 = d0 * rs * gv.x + bv.x;
  const float y1 = d1 * rs * gv.y + bv.y;
  const float y2 = d2 * rs * gv.z + bv.z;
  const float y3 = d3 * rs * gv.w + bv.w;
  if (OUTF) {
    *(float4*)(yf + base) = make_float4(y0, y1, y2, y3);
  } else {
    union { uint2 u; bf16 h[4]; } o;
    o.h[0] = (bf16)y0; o.h[1] = (bf16)y1; o.h[2] = (bf16)y2; o.h[3] = (bf16)y3;
    *(uint2*)(yb + base) = o.u;
  }
}

extern "C" void kernel_launch(void* const* d_in, const int* in_sizes, int n_in,
                              void* d_out, int out_size, void* d_ws, size_t ws_size,
                              hipStream_t stream) {
  const float* Q  = (const float*)d_in[0];
  const float* K  = (const float*)d_in[1];
  const float* Wq = (const float*)d_in[2];
  const float* bq = (const float*)d_in[3];
  const float* Wk = (const float*)d_in[4];
  const float* bk = (const float*)d_in[5];
  const float* Wv = (const float*)d_in[6];
  const float* bv = (const float*)d_in[7];
  const float* Wo = (const float*)d_in[8];
  const float* bo = (const float*)d_in[9];
  const float* g0 = (const float*)d_in[10];
  const float* b0 = (const float*)d_in[11];
  const float* g1 = (const float*)d_in[12];
  const float* b1 = (const float*)d_in[13];
  float* out = (float*)d_out;

  char* ws = (char*)d_ws;
  const size_t MB = 1024 * 1024;
  bf16* Qb    = (bf16*)(ws + 0);          // 16MB
  bf16* Kb    = (bf16*)(ws + 16 * MB);    // 16MB
  bf16* Wqt   = (bf16*)(ws + 32 * MB);    // 2MB
  bf16* Wkvt  = (bf16*)(ws + 34 * MB);    // 4MB ([2048][1024])
  bf16* Wot   = (bf16*)(ws + 38 * MB);    // 2MB
  bf16* qb    = (bf16*)(ws + 40 * MB);    // 16MB
  bf16* kvb   = (bf16*)(ws + 56 * MB);    // 32MB (K half used; V half unused)
  bf16* vT    = (bf16*)(ws + 88 * MB);    // 16MB
  bf16* attnb = (bf16*)(ws + 104 * MB);   // 16MB
  bf16* h0b   = (bf16*)(ws + 56 * MB);    // reuse kvb (dead after attn)
  bf16* out1b = (bf16*)(ws + 0);          // reuse Qb (dead after q GEMM)

  // 1. prep: weight transpose+cvt (z<4) and Q/K->bf16 (z=4,5) in one dispatch
  prep_kernel<<<dim3(16, 16, 6), 256, 0, stream>>>(
      Wq, Wk, Wv, Wo, Wqt, Wkvt, Wkvt + 1024 * 1024, Wot, Q, K, Qb, Kb);
  // 2. projections (q *= 1/32 exact; k *= log2e); V written directly as vT
  gemm16w_kv<<<512, 512, 0, stream>>>(Kb, Wkvt, bk, bv, kvb, vT);
  gemm3b<0><<<512, 256, 0, stream>>>(Qb, Wqt, bq, qb, nullptr, 0.03125f);
  // 3. attention (normalized bf16 out, XCD-remapped grid)
  attn_kernel<<<512, 512, 0, stream>>>(qb, kvb, vT, attnb);
  // 4. h0 = LN(32*qb + attn)
  ln_kernel<true, false><<<8192, 256, 0, stream>>>(attnb, qb, 32.0f, g0, b0, h0b, nullptr);
  // 5. out1 = h0 + relu(h0 @ Wo + bo)
  gemm3b<1><<<512, 256, 0, stream>>>(h0b, Wot, bo, out1b, h0b, 1.0f);
  // 6. out = LN(out1)
  ln_kernel<false, true><<<8192, 256, 0, stream>>>(out1b, nullptr, 0.f, g1, b1, nullptr, out);
}

// Round 22
// 165.034 us; speedup vs baseline: 1.0856x; 1.0372x over previous
//
#include <hip/hip_runtime.h>
#include <hip/hip_bf16.h>
#include <stdint.h>

// Problem dims
#define NB 8
#define NSQ 1024
#define NSK 1024
#define ND 1024
#define NH 16
#define NDH 64
#define NM (NB * NSQ)   // 8192 rows
#define LOG2E 1.4426950408889634f

typedef __bf16 bf16;
typedef __bf16 bf16x8 __attribute__((ext_vector_type(8)));
typedef float f32x4 __attribute__((ext_vector_type(4)));
typedef float f32x16 __attribute__((ext_vector_type(16)));
typedef unsigned int uint32;

// ---------------- async global->LDS (16B per lane) ----------------
__device__ __forceinline__ void async_load16(const void* g, void* l) {
  __builtin_amdgcn_global_load_lds(
      (__attribute__((address_space(1))) void*)g,
      (__attribute__((address_space(3))) void*)l, 16, 0, 0);
}

// half-swap: x' = {x.lo, y.lo}, y' = {x.hi, y.hi}
__device__ __forceinline__ void permswap(uint32& x, uint32& y) {
#if __has_builtin(__builtin_amdgcn_permlane32_swap)
  auto r = __builtin_amdgcn_permlane32_swap(x, y, false, false);
  x = r[0]; y = r[1];
#else
  asm volatile("v_permlane32_swap_b32 %0, %1" : "+v"(x), "+v"(y));
#endif
}

// ---------------- prep: 4x weight transpose+cvt (z<4) + Q/K cvt (z=4,5) ----------------
__global__ __launch_bounds__(256) void prep_kernel(
    const float* __restrict__ W0, const float* __restrict__ W1,
    const float* __restrict__ W2, const float* __restrict__ W3,
    bf16* __restrict__ O0, bf16* __restrict__ O1,
    bf16* __restrict__ O2, bf16* __restrict__ O3,
    const float* __restrict__ Qf, const float* __restrict__ Kf,
    bf16* __restrict__ Qb, bf16* __restrict__ Kb) {
  if (blockIdx.z >= 4) {
    const float* in = (blockIdx.z == 4) ? Qf : Kf;
    bf16* out = (blockIdx.z == 4) ? Qb : Kb;
    int base = (blockIdx.y * 16 + blockIdx.x) * 256 + threadIdx.x;  // 0..65535
    for (int i = base; i < 2097152; i += 65536) {
      float4 v = *(const float4*)(in + (size_t)i * 4);
      union { uint64_t u; bf16 h[4]; } o;
      o.h[0] = (bf16)v.x; o.h[1] = (bf16)v.y; o.h[2] = (bf16)v.z; o.h[3] = (bf16)v.w;
      *(uint64_t*)(out + (size_t)i * 4) = o.u;
    }
    return;
  }
  const float* W; bf16* Wt;
  switch (blockIdx.z) {
    case 0: W = W0; Wt = O0; break;
    case 1: W = W1; Wt = O1; break;
    case 2: W = W2; Wt = O2; break;
    default: W = W3; Wt = O3; break;
  }
  __shared__ float t[64][65];
  const int bc = blockIdx.x * 64;
  const int br = blockIdx.y * 64;
  const int tid = threadIdx.x;
  for (int c = tid; c < 1024; c += 256) {
    int r = c >> 4, off = (c & 15) * 4;
    float4 v = *(const float4*)&W[(size_t)(br + r) * 1024 + bc + off];
    t[r][off] = v.x; t[r][off + 1] = v.y; t[r][off + 2] = v.z; t[r][off + 3] = v.w;
  }
  __syncthreads();
  for (int c = tid; c < 512; c += 256) {
    int cc = c >> 3, rr = (c & 7) * 8;
    union { uint4 u; bf16 h[8]; } o;
#pragma unroll
    for (int i = 0; i < 8; ++i) o.h[i] = (bf16)t[rr + i][cc];
    *(uint4*)&Wt[(size_t)(bc + cc) * 1024 + br + rr] = o.u;
  }
}

// ---------------- proj_gemm: KV (blocks 0..511, V->vT fused) + q (512..767) ----------
// All parts: 128x256 block, 8 waves (2M x 4N, 64x64 out each), BK=32, TRIPLE-buffered
// LDS (72 KB raw smem -> 2 blocks/CU = 16 waves/CU), stage AFTER ds_reads, counted
// vmcnt(3), trailing lgkm0+barrier, granule-XOR swizzle, per-part bijective XCD
// swizzle. q blocks backfill the CUs as KV blocks drain.
// KV K-half epilogue: kvout[row*2048+col] = (acc+bk)*LOG2E.
// KV V-half epilogue: acc+bv transposed via LDS [256][132] -> coalesced vT writes.
// q epilogue: qout[row*1024+col] = (acc+bq)/32.
__global__ __launch_bounds__(512, 4) void proj_gemm(
    const bf16* __restrict__ Qb, const bf16* __restrict__ Kb,
    const bf16* __restrict__ Wqt, const bf16* __restrict__ Wkvt,
    const float* __restrict__ bq_, const float* __restrict__ bk_,
    const float* __restrict__ bv_,
    bf16* __restrict__ qout, bf16* __restrict__ kvout, bf16* __restrict__ vT) {
  constexpr int NT = 32;                 // K = 1024 = 32 x 32
  __shared__ __align__(16) char smem[73728];          // 72 KB
  bf16 (*Asl)[128 * 32] = (bf16(*)[128 * 32])smem;            // 3 x 8 KB
  bf16 (*Bsl)[256 * 32] = (bf16(*)[256 * 32])(smem + 24576);  // 3 x 16 KB
  bf16* Vt = (bf16*)smem;                             // epilogue view [256][132]

  const int tid = threadIdx.x;
  const bool isQ = (blockIdx.x >= 512);
  const bf16* Ab; const bf16* Bt;
  int bcol, brow;
  if (!isQ) {
    const int f = blockIdx.x;
    const int xi = (f & 7) * 64 + (f >> 3);       // 512 blocks -> bijective
    bcol = (xi & 7) * 256; brow = (xi >> 3) * 128;
    Ab = Kb; Bt = Wkvt;
  } else {
    const int f = blockIdx.x - 512;
    const int xi = (f & 7) * 32 + (f >> 3);       // 256 blocks -> bijective
    bcol = (xi & 3) * 256; brow = (xi >> 2) * 128;
    Ab = Qb; Bt = Wqt;
  }

  const int w = tid >> 6, lane = tid & 63;
  const int wm = w >> 2, wn = w & 3;              // 2M x 4N waves
  const int lr = lane & 15, l4 = lane >> 4;
  const int rgrp = l4 * 4;
  const int gph = (l4 ^ ((lr >> 1) & 3)) * 8;     // read-side swizzled granule

  const int srow = tid >> 2;                      // 0..127
  const int gsrc = (tid & 3) ^ ((tid >> 3) & 3);
  const bf16* Ag = Ab + (size_t)(brow + srow) * 1024 + gsrc * 8;
  const bf16* Bg = Bt + (size_t)(bcol + srow) * 1024 + gsrc * 8;
  const int ldo = srow * 32 + (tid & 3) * 8;

  auto stage = [&](int d, int kt) {   // 1 A round + 2 B rounds = 3 loads/thread
    async_load16(Ag + kt * 32, &Asl[d][ldo]);
#pragma unroll
    for (int r = 0; r < 2; ++r)
      async_load16(Bg + (size_t)r * (128 * 1024) + kt * 32, &Bsl[d][r * 4096 + ldo]);
  };

  f32x4 acc[4][4] = {};

  stage(0, 0);
  stage(1, 1);
  asm volatile("s_waitcnt vmcnt(3)" ::: "memory");   // tile 0 landed
  __builtin_amdgcn_s_barrier();

  int cur = 0, st2 = 2;
  for (int t = 0; t < NT; ++t) {
    bf16x8 af[4], bfr[4];
#pragma unroll
    for (int i = 0; i < 4; ++i)
      af[i] = *(const bf16x8*)&Asl[cur][(wm * 64 + i * 16 + lr) * 32 + gph];
#pragma unroll
    for (int n = 0; n < 4; ++n)
      bfr[n] = *(const bf16x8*)&Bsl[cur][(wn * 64 + n * 16 + lr) * 32 + gph];
    if (t + 2 < NT) stage(st2, t + 2);   // buffer last read at t-1 (pinned)
    __builtin_amdgcn_s_setprio(1);
#pragma unroll
    for (int i = 0; i < 4; ++i)
#pragma unroll
      for (int n = 0; n < 4; ++n)
        acc[i][n] = __builtin_amdgcn_mfma_f32_16x16x32_bf16(af[i], bfr[n], acc[i][n], 0, 0, 0);
    __builtin_amdgcn_s_setprio(0);
    if (t + 2 < NT)      asm volatile("s_waitcnt vmcnt(3)" ::: "memory");
    else if (t + 1 < NT) asm volatile("s_waitcnt vmcnt(0)" ::: "memory");
    asm volatile("s_waitcnt lgkmcnt(0)" ::: "memory");
    __builtin_amdgcn_s_barrier();
    cur = (cur == 2) ? 0 : cur + 1;
    st2 = (st2 == 2) ? 0 : st2 + 1;
  }
  // after the final barrier all LDS reads are drained -> smem reusable

  if (isQ) {
    // ---------------- q epilogue: (acc+bq)/32, row-major ----------------
#pragma unroll
    for (int m = 0; m < 4; ++m) {
#pragma unroll
      for (int n = 0; n < 4; ++n) {
        const int col = bcol + wn * 64 + n * 16 + lr;
        const float bvv = bq_[col];
#pragma unroll
        for (int r = 0; r < 4; ++r) {
          const int row = brow + wm * 64 + m * 16 + rgrp + r;
          qout[(size_t)row * 1024 + col] = (bf16)((acc[m][n][r] + bvv) * 0.03125f);
        }
      }
    }
  } else if (bcol < 1024) {
    // ---------------- K epilogue (row-major into kv K-half) ----------------
#pragma unroll
    for (int m = 0; m < 4; ++m) {
#pragma unroll
      for (int n = 0; n < 4; ++n) {
        const int col = bcol + wn * 64 + n * 16 + lr;
        const float bvv = bk_[col];
#pragma unroll
        for (int r = 0; r < 4; ++r) {
          const int row = brow + wm * 64 + m * 16 + rgrp + r;
          kvout[(size_t)row * 2048 + col] = (bf16)((acc[m][n][r] + bvv) * LOG2E);
        }
      }
    }
  } else {
    // ---------------- V epilogue: transpose via LDS, write vT ----------------
#pragma unroll
    for (int m = 0; m < 4; ++m) {
#pragma unroll
      for (int n = 0; n < 4; ++n) {
        const int cl = wn * 64 + n * 16 + lr;          // col_local 0..255
        const float bvv = bv_[(bcol - 1024) + cl];
        const int rl = wm * 64 + m * 16 + rgrp;        // row_local base
#pragma unroll
        for (int r = 0; r < 4; ++r)
          Vt[cl * 132 + rl + r] = (bf16)(acc[m][n][r] + bvv);
      }
    }
    asm volatile("s_waitcnt lgkmcnt(0)" ::: "memory");
    __builtin_amdgcn_s_barrier();
    // write-out: 512 threads x half-row (64 s = 128B contiguous) each
    const int orow = tid >> 1;                         // col_local 0..255
    const int half = tid & 1;
    const int colV = (bcol - 1024) + orow;
    const int h = colV >> 6, d = colV & 63;
    const int bb = brow >> 10;
    const int s0 = (brow & 1023) + half * 64;
    bf16* dst = vT + ((size_t)((bb * 16 + h) * 64 + d)) * NSK + s0;
    const bf16* src = &Vt[orow * 132 + half * 64];
#pragma unroll
    for (int c = 0; c < 8; ++c)
      *(uint4*)(dst + c * 8) = *(const uint4*)(src + c * 8);
  }
}

// ---------------- gemm3b: Wo GEMM (bf16 A, R10-proven) ----------------
// 128 x 128 block, 4 waves (2x2), BK=32, TRIPLE-buffered LDS, one barrier + counted
// vmcnt per K-tile, 2-tile-deep prefetch (stage AFTER ds_reads), granule-XOR swizzle.
// Cb = bf16(Res + relu(acc+bias)).
__global__ __launch_bounds__(256, 2) void gemm_wo(
    const bf16* __restrict__ Ab, const bf16* __restrict__ Bt,
    const float* __restrict__ bias,
    bf16* __restrict__ Cb, const bf16* __restrict__ Resb) {
  constexpr int NT = 32;
  __shared__ __align__(16) bf16 Asl[3][128 * 32];
  __shared__ __align__(16) bf16 Bsl[3][128 * 32];

  const int tid = threadIdx.x;
  const int flat = blockIdx.x;
  const int xi = (flat & 7) * 64 + (flat >> 3);
  const int bcol = (xi & 7) * 128;
  const int brow = (xi >> 3) * 128;

  const int w = tid >> 6, lane = tid & 63;
  const int wm = w >> 1, wn = w & 1;
  const int lr = lane & 15, l4 = lane >> 4;
  const int rgrp = l4 * 4;
  const int gph = (l4 ^ ((lr >> 1) & 3)) * 8;

  const int srow = tid >> 2;
  const int gsrc = (tid & 3) ^ ((tid >> 3) & 3);
  const bf16* Ag = Ab + (size_t)(brow + srow) * 1024 + gsrc * 8;
  const bf16* Bg = Bt + (size_t)(bcol + srow) * 1024 + gsrc * 8;
  const int ldo = srow * 32 + (tid & 3) * 8;

  auto stage = [&](int d, int kt) {
#pragma unroll
    for (int r = 0; r < 2; ++r)
      async_load16(Ag + (size_t)r * (64 * 1024) + kt * 32, &Asl[d][r * 2048 + ldo]);
#pragma unroll
    for (int r = 0; r < 2; ++r)
      async_load16(Bg + (size_t)r * (64 * 1024) + kt * 32, &Bsl[d][r * 2048 + ldo]);
  };

  f32x4 acc[4][4] = {};

  stage(0, 0);
  stage(1, 1);
  asm volatile("s_waitcnt vmcnt(4)" ::: "memory");
  __builtin_amdgcn_s_barrier();

  int cur = 0, st2 = 2;
  for (int t = 0; t < NT; ++t) {
    bf16x8 af[4], bfr[4];
#pragma unroll
    for (int i = 0; i < 4; ++i)
      af[i] = *(const bf16x8*)&Asl[cur][(wm * 64 + i * 16 + lr) * 32 + gph];
#pragma unroll
    for (int n = 0; n < 4; ++n)
      bfr[n] = *(const bf16x8*)&Bsl[cur][(wn * 64 + n * 16 + lr) * 32 + gph];
    if (t + 2 < NT) stage(st2, t + 2);
    __builtin_amdgcn_s_setprio(1);
#pragma unroll
    for (int i = 0; i < 4; ++i)
#pragma unroll
      for (int n = 0; n < 4; ++n)
        acc[i][n] = __builtin_amdgcn_mfma_f32_16x16x32_bf16(af[i], bfr[n], acc[i][n], 0, 0, 0);
    __builtin_amdgcn_s_setprio(0);
    if (t + 2 < NT)      asm volatile("s_waitcnt vmcnt(4)" ::: "memory");
    else if (t + 1 < NT) asm volatile("s_waitcnt vmcnt(0)" ::: "memory");
    asm volatile("s_waitcnt lgkmcnt(0)" ::: "memory");
    __builtin_amdgcn_s_barrier();
    cur = (cur == 2) ? 0 : cur + 1;
    st2 = (st2 == 2) ? 0 : st2 + 1;
  }

#pragma unroll
  for (int m = 0; m < 4; ++m) {
#pragma unroll
    for (int n = 0; n < 4; ++n) {
      const int col = bcol + wn * 64 + n * 16 + lr;
      const float bv = bias[col];
#pragma unroll
      for (int r = 0; r < 4; ++r) {
        const int row = brow + wm * 64 + m * 16 + rgrp + r;
        float v = acc[m][n][r] + bv;
        float res = (float)Resb[(size_t)row * 1024 + col];
        Cb[(size_t)row * 1024 + col] = (bf16)(res + (v > 0.f ? v : 0.f));
      }
    }
  }
}

// ---------------- fused attention: 8 waves x 32 q, 32x32 MFMA, in-register P ----------
// 1-D grid of 512 blocks, XCD-remapped so all 4 q-blocks of one (b,h) share an XCD
// (K/V panels L2-resident; verified FETCH 73.8 -> 24.6 MB).
__global__ __launch_bounds__(512, 4) void attn_kernel(
    const bf16* __restrict__ qb, const bf16* __restrict__ kvb,
    const bf16* __restrict__ vT, bf16* __restrict__ attnout) {
  const int bid = blockIdx.x;
  const int bh = (bid & 7) * 16 + ((bid >> 3) & 15);
  const int qi = bid >> 7;
  const int b = bh >> 4, h = bh & 15;
  const int tid = threadIdx.x, w = tid >> 6, lane = tid & 63;
  const int l31 = lane & 31;
  const int l1 = lane >> 5;
  const int q0w = qi * 256 + w * 32;

  __shared__ __align__(16) bf16 Kl[2][64 * 64];
  __shared__ __align__(16) bf16 Vl[2][64 * 64];

  const int srow = tid >> 3;
  const int sgran = tid & 7;
  const int gsw = sgran ^ (srow & 7);
  const int ldst = srow * 64 + sgran * 8;
  const int rg = l31 & 7;

  const bf16* kbase = kvb + (size_t)(b * NSK) * 2048 + h * NDH;
  const bf16* vbase = vT + (size_t)(bh * NDH) * NSK;

  bf16x8 qf[4];
#pragma unroll
  for (int kd = 0; kd < 4; ++kd)
    qf[kd] = *(const bf16x8*)&qb[(size_t)(b * NSQ + q0w + l31) * ND +
                                 h * NDH + kd * 16 + l1 * 8];

  f32x16 oacc0 = {}, oacc1 = {}, lacc = {};
  bf16x8 ones;
#pragma unroll
  for (int i = 0; i < 8; ++i) ones[i] = (bf16)1.0f;

  auto stage = [&](int bi, int kt) {
    async_load16(kbase + (size_t)(kt + srow) * 2048 + gsw * 8, &Kl[bi][ldst]);
    async_load16(vbase + (size_t)srow * NSK + kt + gsw * 8, &Vl[bi][ldst]);
  };

  stage(0, 0);

  for (int t = 0; t < 16; ++t) {
    const int bi = t & 1;
    asm volatile("s_waitcnt vmcnt(0)" ::: "memory");
    __syncthreads();
    if (t < 15) stage(bi ^ 1, (t + 1) * 64);

    uint32 W[2][4][2];
#pragma unroll
    for (int n = 0; n < 2; ++n) {
      f32x16 s = {};
      __builtin_amdgcn_s_setprio(1);
#pragma unroll
      for (int kd = 0; kd < 4; ++kd) {
        bf16x8 kf = *(const bf16x8*)&Kl[bi][(n * 32 + l31) * 64 + (((kd * 2 + l1) ^ rg) * 8)];
        s = __builtin_amdgcn_mfma_f32_32x32x16_bf16(kf, qf[kd], s, 0, 0, 0);
      }
      __builtin_amdgcn_s_setprio(0);
#pragma unroll
      for (int r2 = 0; r2 < 4; ++r2)
#pragma unroll
        for (int p = 0; p < 2; ++p) {
          float elo = __builtin_amdgcn_exp2f(s[r2 * 4 + 2 * p]);
          float ehi = __builtin_amdgcn_exp2f(s[r2 * 4 + 2 * p + 1]);
          uint32 wd;
          asm("v_cvt_pk_bf16_f32 %0, %1, %2" : "=v"(wd) : "v"(elo), "v"(ehi));
          W[n][r2][p] = wd;
        }
    }
    __builtin_amdgcn_s_setprio(1);
#pragma unroll
    for (int kc = 0; kc < 4; ++kc) {
      uint32 x0 = W[kc >> 1][(kc & 1) * 2][0], y0 = W[kc >> 1][(kc & 1) * 2 + 1][0];
      uint32 x1 = W[kc >> 1][(kc & 1) * 2][1], y1 = W[kc >> 1][(kc & 1) * 2 + 1][1];
      permswap(x0, y0);
      permswap(x1, y1);
      union { uint32 u[4]; bf16x8 v; } cvt;
      cvt.u[0] = x0; cvt.u[1] = x1; cvt.u[2] = y0; cvt.u[3] = y1;
      bf16x8 pa = cvt.v;
      bf16x8 vf0 = *(const bf16x8*)&Vl[bi][(l31) * 64 + (((kc * 2 + l1) ^ rg) * 8)];
      bf16x8 vf1 = *(const bf16x8*)&Vl[bi][(32 + l31) * 64 + (((kc * 2 + l1) ^ rg) * 8)];
      oacc0 = __builtin_amdgcn_mfma_f32_32x32x16_bf16(pa, vf0, oacc0, 0, 0, 0);
      oacc1 = __builtin_amdgcn_mfma_f32_32x32x16_bf16(pa, vf1, oacc1, 0, 0, 0);
      lacc = __builtin_amdgcn_mfma_f32_32x32x16_bf16(pa, ones, lacc, 0, 0, 0);
    }
    __builtin_amdgcn_s_setprio(0);
  }

  float inv[16];
#pragma unroll
  for (int r = 0; r < 16; ++r) inv[r] = 1.0f / lacc[r];
#pragma unroll
  for (int r = 0; r < 16; ++r) {
    const int row = q0w + (r & 3) + 8 * (r >> 2) + 4 * l1;
    attnout[(size_t)(b * NSQ + row) * ND + h * NDH + l31] = (bf16)(oacc0[r] * inv[r]);
    attnout[(size_t)(b * NSQ + row) * ND + h * NDH + 32 + l31] = (bf16)(oacc1[r] * inv[r]);
  }
}

// ---------------- LayerNorm over bf16 input ----------------
template <bool RES, bool OUTF>
__global__ __launch_bounds__(256) void ln_kernel(
    const bf16* __restrict__ x, const bf16* __restrict__ rq, float rscale,
    const float* __restrict__ g, const float* __restrict__ be,
    bf16* __restrict__ yb, float* __restrict__ yf) {
  __shared__ float sm[4];
  const int row = blockIdx.x, tid = threadIdx.x;
  const size_t base = (size_t)row * ND + tid * 4;
  union { uint2 u; bf16 h[4]; } xv;
  xv.u = *(const uint2*)(x + base);
  float v0 = (float)xv.h[0], v1 = (float)xv.h[1], v2 = (float)xv.h[2], v3 = (float)xv.h[3];
  if (RES) {
    union { uint2 u; bf16 h[4]; } q;
    q.u = *(const uint2*)(rq + base);
    v0 += rscale * (float)q.h[0]; v1 += rscale * (float)q.h[1];
    v2 += rscale * (float)q.h[2]; v3 += rscale * (float)q.h[3];
  }
  float s = v0 + v1 + v2 + v3;
#pragma unroll
  for (int off = 32; off > 0; off >>= 1) s += __shfl_down(s, off, 64);
  if ((tid & 63) == 0) sm[tid >> 6] = s;
  __syncthreads();
  const float mean = (sm[0] + sm[1] + sm[2] + sm[3]) * (1.0f / ND);
  __syncthreads();
  const float d0 = v0 - mean, d1 = v1 - mean, d2 = v2 - mean, d3 = v3 - mean;
  float sq = d0 * d0 + d1 * d1 + d2 * d2 + d3 * d3;
#pragma unroll
  for (int off = 32; off > 0; off >>= 1) sq += __shfl_down(sq, off, 64);
  if ((tid & 63) == 0) sm[tid >> 6] = sq;
  __syncthreads();
  const float var = (sm[0] + sm[1] + sm[2] + sm[3]) * (1.0f / ND);
  const float rs = rsqrtf(var + 1e-5f);
  float4 gv = *(const float4*)(g + tid * 4);
  float4 bv = *(const float4*)(be + tid * 4);
  const float y0 = d0 * rs * gv.x + bv.x;
  const float y1 = d1 * rs * gv.y + bv.y;
  const float y2 = d2 * rs * gv.z + bv.z;
  const float y3 = d3 * rs * gv.w + bv.w;
  if (OUTF) {
    *(float4*)(yf + base) = make_float4(y0, y1, y2, y3);
  } else {
    union { uint2 u; bf16 h[4]; } o;
    o.h[0] = (bf16)y0; o.h[1] = (bf16)y1; o.h[2] = (bf16)y2; o.h[3] = (bf16)y3;
    *(uint2*)(yb + base) = o.u;
  }
}

extern "C" void kernel_launch(void* const* d_in, const int* in_sizes, int n_in,
                              void* d_out, int out_size, void* d_ws, size_t ws_size,
                              hipStream_t stream) {
  const float* Q  = (const float*)d_in[0];
  const float* K  = (const float*)d_in[1];
  const float* Wq = (const float*)d_in[2];
  const float* bq = (const float*)d_in[3];
  const float* Wk = (const float*)d_in[4];
  const float* bk = (const float*)d_in[5];
  const float* Wv = (const float*)d_in[6];
  const float* bv = (const float*)d_in[7];
  const float* Wo = (const float*)d_in[8];
  const float* bo = (const float*)d_in[9];
  const float* g0 = (const float*)d_in[10];
  const float* b0 = (const float*)d_in[11];
  const float* g1 = (const float*)d_in[12];
  const float* b1 = (const float*)d_in[13];
  float* out = (float*)d_out;

  char* ws = (char*)d_ws;
  const size_t MB = 1024 * 1024;
  bf16* Qb    = (bf16*)(ws + 0);          // 16MB
  bf16* Kb    = (bf16*)(ws + 16 * MB);    // 16MB
  bf16* Wqt   = (bf16*)(ws + 32 * MB);    // 2MB
  bf16* Wkvt  = (bf16*)(ws + 34 * MB);    // 4MB ([2048][1024])
  bf16* Wot   = (bf16*)(ws + 38 * MB);    // 2MB
  bf16* qb    = (bf16*)(ws + 40 * MB);    // 16MB
  bf16* kvb   = (bf16*)(ws + 56 * MB);    // 32MB (K half used)
  bf16* vT    = (bf16*)(ws + 88 * MB);    // 16MB
  bf16* attnb = (bf16*)(ws + 104 * MB);   // 16MB
  bf16* h0b   = (bf16*)(ws + 56 * MB);    // reuse kvb (dead after attn)
  bf16* out1b = (bf16*)(ws + 0);          // reuse Qb (dead after proj)

  // 1. prep: weight transpose+cvt (z<4) and Q/K->bf16 (z=4,5) in one dispatch
  prep_kernel<<<dim3(16, 16, 6), 256, 0, stream>>>(
      Wq, Wk, Wv, Wo, Wqt, Wkvt, Wkvt + 1024 * 1024, Wot, Q, K, Qb, Kb);
  // 2. fused projections: KV (512 blocks, V->vT fused) + q (256 blocks) overlap
  proj_gemm<<<768, 512, 0, stream>>>(Qb, Kb, Wqt, Wkvt, bq, bk, bv, qb, kvb, vT);
  // 3. attention (normalized bf16 out, XCD-remapped grid)
  attn_kernel<<<512, 512, 0, stream>>>(qb, kvb, vT, attnb);
  // 4. h0 = LN(32*qb + attn)
  ln_kernel<true, false><<<8192, 256, 0, stream>>>(attnb, qb, 32.0f, g0, b0, h0b, nullptr);
  // 5. out1 = h0 + relu(h0 @ Wo + bo)
  gemm_wo<<<512, 256, 0, stream>>>(h0b, Wot, bo, out1b, h0b);
  // 6. out = LN(out1)
  ln_kernel<false, true><<<8192, 256, 0, stream>>>(out1b, nullptr, 0.f, g1, b1, nullptr, out);
}